// Round 1
// baseline (6163.523 us; speedup 1.0000x reference)
//
#include <hip/hip_runtime.h>

// Problem constants (B=8, C=inter=256, H=W=128, patches 8x8 -> 2048 patches of 64 tokens)
constexpr int kHW = 128;
constexpr int kC  = 256;
constexpr int kB  = 8;

using u16 = unsigned short;
using u32 = unsigned int;

__device__ __forceinline__ void unpack8(const int4 v, float f[8]) {
  u32 a = (u32)v.x, b = (u32)v.y, c = (u32)v.z, d = (u32)v.w;
  f[0] = __uint_as_float(a << 16);
  f[1] = __uint_as_float(a & 0xffff0000u);
  f[2] = __uint_as_float(b << 16);
  f[3] = __uint_as_float(b & 0xffff0000u);
  f[4] = __uint_as_float(c << 16);
  f[5] = __uint_as_float(c & 0xffff0000u);
  f[6] = __uint_as_float(d << 16);
  f[7] = __uint_as_float(d & 0xffff0000u);
}

__device__ __forceinline__ u16 f2bf(float f) {
  u32 u = __float_as_uint(f);
  u32 r = u + 0x7fffu + ((u >> 16) & 1u);
  return (u16)(r >> 16);
}

// ---------------------------------------------------------------------------
// Direct 3x3 SAME conv, fp32 in -> bf16 out.
// Block: 256 thr. Tile: 16 oc x 8 rows x 128 cols. Thread: 2x2 pixels x 16 oc.
// Weights are read via block-uniform addresses -> scalar loads (no LDS needed).
// ---------------------------------------------------------------------------
__global__ __launch_bounds__(256) void conv3x3_kernel(
    const float* __restrict__ x, const float* __restrict__ w, u16* __restrict__ y)
{
  __shared__ float tin[10][132];
  const int t   = threadIdx.x;
  const int oc0 = blockIdx.x * 16;
  const int y0  = blockIdx.y * 8;
  const int b   = blockIdx.z;
  const int tx  = t & 63, ty = t >> 6;
  const int x0  = tx * 2;

  float acc[16][2][2];
#pragma unroll
  for (int i = 0; i < 16; ++i) {
    acc[i][0][0] = 0.f; acc[i][0][1] = 0.f; acc[i][1][0] = 0.f; acc[i][1][1] = 0.f;
  }

  const float* xb = x + (size_t)(b * kC) * (kHW * kHW);

  for (int c = 0; c < kC; ++c) {
    __syncthreads();
    const float* xc = xb + (size_t)c * (kHW * kHW);
#pragma unroll
    for (int i = 0; i < 6; ++i) {
      int idx = t + i * 256;
      if (idx < 1320) {
        int r  = idx / 132;
        int cc = idx - r * 132;
        int gy = y0 - 1 + r, gx = cc - 1;
        float v = 0.f;
        if (gy >= 0 && gy < kHW && gx >= 0 && gx < kHW) v = xc[gy * kHW + gx];
        tin[r][cc] = v;
      }
    }
    __syncthreads();

    float iv[4][4];
#pragma unroll
    for (int r = 0; r < 4; ++r)
#pragma unroll
      for (int q = 0; q < 4; ++q)
        iv[r][q] = tin[ty * 2 + r][x0 + q];

    const float* wc = w + (size_t)(oc0 * kC + c) * 9;
#pragma unroll
    for (int oc = 0; oc < 16; ++oc) {
      const float* wo = wc + oc * (kC * 9);
      float w0 = wo[0], w1 = wo[1], w2 = wo[2], w3 = wo[3], w4 = wo[4],
            w5 = wo[5], w6 = wo[6], w7 = wo[7], w8 = wo[8];
#pragma unroll
      for (int py = 0; py < 2; ++py)
#pragma unroll
        for (int px = 0; px < 2; ++px) {
          float s = acc[oc][py][px];
          s = fmaf(iv[py + 0][px + 0], w0, s);
          s = fmaf(iv[py + 0][px + 1], w1, s);
          s = fmaf(iv[py + 0][px + 2], w2, s);
          s = fmaf(iv[py + 1][px + 0], w3, s);
          s = fmaf(iv[py + 1][px + 1], w4, s);
          s = fmaf(iv[py + 1][px + 2], w5, s);
          s = fmaf(iv[py + 2][px + 0], w6, s);
          s = fmaf(iv[py + 2][px + 1], w7, s);
          s = fmaf(iv[py + 2][px + 2], w8, s);
          acc[oc][py][px] = s;
        }
    }
  }

#pragma unroll
  for (int oc = 0; oc < 16; ++oc)
#pragma unroll
    for (int py = 0; py < 2; ++py) {
      size_t o = (((size_t)(b * kC + oc0 + oc)) * kHW + (y0 + ty * 2 + py)) * kHW + x0;
      u32 pack = (u32)f2bf(acc[oc][py][0]) | ((u32)f2bf(acc[oc][py][1]) << 16);
      *reinterpret_cast<u32*>(y + o) = pack;
    }
}

// ---------------------------------------------------------------------------
// GroupNorm stats: one block per (b, g). 8 ch x 16384 px. Writes mean, rstd.
// stat layout: stat[0..255] = mean, stat[256..511] = rstd  (index b*32+g)
// ---------------------------------------------------------------------------
__global__ __launch_bounds__(256) void gnstats_kernel(
    const u16* __restrict__ y, float* __restrict__ stat)
{
  const int bg = blockIdx.x;
  const int t  = threadIdx.x;
  const int4* base = reinterpret_cast<const int4*>(y + (size_t)bg * (8 * 16384));
  float s = 0.f, ss = 0.f;
  for (int i = t; i < 16384; i += 256) {
    int4 v = base[i];
    float f[8]; unpack8(v, f);
#pragma unroll
    for (int j = 0; j < 8; ++j) { s += f[j]; ss = fmaf(f[j], f[j], ss); }
  }
#pragma unroll
  for (int off = 32; off >= 1; off >>= 1) {
    s  += __shfl_down(s, off);
    ss += __shfl_down(ss, off);
  }
  __shared__ float ls[4], lss[4];
  if ((t & 63) == 0) { ls[t >> 6] = s; lss[t >> 6] = ss; }
  __syncthreads();
  if (t == 0) {
    float S  = ls[0] + ls[1] + ls[2] + ls[3];
    float SS = lss[0] + lss[1] + lss[2] + lss[3];
    float mean = S * (1.f / 131072.f);
    float var  = SS * (1.f / 131072.f) - mean * mean;
    stat[bg]       = mean;
    stat[256 + bg] = rsqrtf(var + 1e-5f);
  }
}

// ---------------------------------------------------------------------------
// Per-patch attention. One block per patch (2048 blocks), 256 threads.
// q,k staged per 64-channel chunk with GN applied on load. Softmax in
// registers via 4-lane shuffle groups. Writes attn_out + x_low to `out`.
// ---------------------------------------------------------------------------
__global__ __launch_bounds__(256) void attn_kernel(
    const u16* __restrict__ yq, const u16* __restrict__ yk,
    const float* __restrict__ statq, const float* __restrict__ statk,
    const float* __restrict__ gqw, const float* __restrict__ gqb,
    const float* __restrict__ gkw, const float* __restrict__ gkb,
    const float* __restrict__ x_low, float* __restrict__ out)
{
  __shared__ float qch[64][68];
  __shared__ float kch[64][68];
  __shared__ float P[64][65];

  const int n  = blockIdx.x;
  const int b  = n >> 8;
  const int ph = (n >> 4) & 15;
  const int pw = n & 15;
  const int y0 = ph * 8, x0 = pw * 8;
  const int t  = threadIdx.x;
  const int row_i = t >> 2, jq = t & 3;

  float S[16];
#pragma unroll
  for (int j = 0; j < 16; ++j) S[j] = 0.f;

  // ---- QK^T over 4 channel chunks ----
  for (int cc = 0; cc < 4; ++cc) {
    __syncthreads();
#pragma unroll
    for (int rr = 0; rr < 2; ++rr) {
      int r  = t + rr * 256;
      int cl = r >> 3, py = r & 7;
      int c  = cc * 64 + cl;
      int g  = c >> 3;
      size_t pixoff = (((size_t)(b * kC + c)) * kHW + (y0 + py)) * kHW + x0;
      {
        float mean = statq[b * 32 + g], rstd = statq[256 + b * 32 + g];
        float A  = rstd * gqw[c];
        float Bv = fmaf(-mean, A, gqb[c]);
        int4 v = *reinterpret_cast<const int4*>(yq + pixoff);
        float f[8]; unpack8(v, f);
        float4 o0 = make_float4(fmaf(f[0],A,Bv), fmaf(f[1],A,Bv), fmaf(f[2],A,Bv), fmaf(f[3],A,Bv));
        float4 o1 = make_float4(fmaf(f[4],A,Bv), fmaf(f[5],A,Bv), fmaf(f[6],A,Bv), fmaf(f[7],A,Bv));
        *reinterpret_cast<float4*>(&qch[cl][py * 8])     = o0;
        *reinterpret_cast<float4*>(&qch[cl][py * 8 + 4]) = o1;
      }
      {
        float mean = statk[b * 32 + g], rstd = statk[256 + b * 32 + g];
        float A  = rstd * gkw[c];
        float Bv = fmaf(-mean, A, gkb[c]);
        int4 v = *reinterpret_cast<const int4*>(yk + pixoff);
        float f[8]; unpack8(v, f);
        float4 o0 = make_float4(fmaf(f[0],A,Bv), fmaf(f[1],A,Bv), fmaf(f[2],A,Bv), fmaf(f[3],A,Bv));
        float4 o1 = make_float4(fmaf(f[4],A,Bv), fmaf(f[5],A,Bv), fmaf(f[6],A,Bv), fmaf(f[7],A,Bv));
        *reinterpret_cast<float4*>(&kch[cl][py * 8])     = o0;
        *reinterpret_cast<float4*>(&kch[cl][py * 8 + 4]) = o1;
      }
    }
    __syncthreads();
#pragma unroll 4
    for (int c = 0; c < 64; ++c) {
      float qv = qch[c][row_i];
      const float* kr = &kch[c][jq * 16];
      float4 k0 = *reinterpret_cast<const float4*>(kr);
      float4 k1 = *reinterpret_cast<const float4*>(kr + 4);
      float4 k2 = *reinterpret_cast<const float4*>(kr + 8);
      float4 k3 = *reinterpret_cast<const float4*>(kr + 12);
      S[0]  = fmaf(qv, k0.x, S[0]);  S[1]  = fmaf(qv, k0.y, S[1]);
      S[2]  = fmaf(qv, k0.z, S[2]);  S[3]  = fmaf(qv, k0.w, S[3]);
      S[4]  = fmaf(qv, k1.x, S[4]);  S[5]  = fmaf(qv, k1.y, S[5]);
      S[6]  = fmaf(qv, k1.z, S[6]);  S[7]  = fmaf(qv, k1.w, S[7]);
      S[8]  = fmaf(qv, k2.x, S[8]);  S[9]  = fmaf(qv, k2.y, S[9]);
      S[10] = fmaf(qv, k2.z, S[10]); S[11] = fmaf(qv, k2.w, S[11]);
      S[12] = fmaf(qv, k3.x, S[12]); S[13] = fmaf(qv, k3.y, S[13]);
      S[14] = fmaf(qv, k3.z, S[14]); S[15] = fmaf(qv, k3.w, S[15]);
    }
  }

  // ---- softmax over rows (4 lanes per row: lanes t^1, t^2 share row) ----
  float m = S[0];
#pragma unroll
  for (int j = 1; j < 16; ++j) m = fmaxf(m, S[j]);
  m = fmaxf(m, __shfl_xor(m, 1));
  m = fmaxf(m, __shfl_xor(m, 2));
  float sum = 0.f;
#pragma unroll
  for (int j = 0; j < 16; ++j) { S[j] = __expf((S[j] - m) * 0.0625f); sum += S[j]; }
  sum += __shfl_xor(sum, 1);
  sum += __shfl_xor(sum, 2);
  float inv = 1.f / sum;
#pragma unroll
  for (int j = 0; j < 16; ++j) P[row_i][jq * 16 + j] = S[j] * inv;

  // ---- PV: out[i][c] = sum_j P[i][j] * k[c][j] ----
  const int i  = t & 63;
  const int cs = t >> 6;   // wave id: channel sub-block
  float acc[64];
#pragma unroll
  for (int a = 0; a < 64; ++a) acc[a] = 0.f;

#pragma unroll
  for (int cc = 0; cc < 4; ++cc) {
    __syncthreads();   // P visible / previous chunk consumed
#pragma unroll
    for (int rr = 0; rr < 2; ++rr) {
      int r  = t + rr * 256;
      int cl = r >> 3, py = r & 7;
      int c  = cc * 64 + cl;
      int g  = c >> 3;
      size_t pixoff = (((size_t)(b * kC + c)) * kHW + (y0 + py)) * kHW + x0;
      float mean = statk[b * 32 + g], rstd = statk[256 + b * 32 + g];
      float A  = rstd * gkw[c];
      float Bv = fmaf(-mean, A, gkb[c]);
      int4 v = *reinterpret_cast<const int4*>(yk + pixoff);
      float f[8]; unpack8(v, f);
      float4 o0 = make_float4(fmaf(f[0],A,Bv), fmaf(f[1],A,Bv), fmaf(f[2],A,Bv), fmaf(f[3],A,Bv));
      float4 o1 = make_float4(fmaf(f[4],A,Bv), fmaf(f[5],A,Bv), fmaf(f[6],A,Bv), fmaf(f[7],A,Bv));
      *reinterpret_cast<float4*>(&kch[cl][py * 8])     = o0;
      *reinterpret_cast<float4*>(&kch[cl][py * 8 + 4]) = o1;
    }
    __syncthreads();
#pragma unroll
    for (int q4 = 0; q4 < 4; ++q4) {
      float p[16];
#pragma unroll
      for (int jj = 0; jj < 16; ++jj) p[jj] = P[i][q4 * 16 + jj];
#pragma unroll
      for (int k = 0; k < 16; ++k) {
        const float* kr = &kch[cs * 16 + k][q4 * 16];
        float4 k0 = *reinterpret_cast<const float4*>(kr);
        float4 k1 = *reinterpret_cast<const float4*>(kr + 4);
        float4 k2 = *reinterpret_cast<const float4*>(kr + 8);
        float4 k3 = *reinterpret_cast<const float4*>(kr + 12);
        float s = acc[cc * 16 + k];
        s = fmaf(p[0],  k0.x, s); s = fmaf(p[1],  k0.y, s);
        s = fmaf(p[2],  k0.z, s); s = fmaf(p[3],  k0.w, s);
        s = fmaf(p[4],  k1.x, s); s = fmaf(p[5],  k1.y, s);
        s = fmaf(p[6],  k1.z, s); s = fmaf(p[7],  k1.w, s);
        s = fmaf(p[8],  k2.x, s); s = fmaf(p[9],  k2.y, s);
        s = fmaf(p[10], k2.z, s); s = fmaf(p[11], k2.w, s);
        s = fmaf(p[12], k3.x, s); s = fmaf(p[13], k3.y, s);
        s = fmaf(p[14], k3.z, s); s = fmaf(p[15], k3.w, s);
        acc[cc * 16 + k] = s;
      }
    }
  }

  // ---- write attn_out + x_low into out (NCHW) ----
  const int py = i >> 3, px = i & 7;
  const size_t pixbase = ((size_t)b * kC) * (kHW * kHW) + (size_t)(y0 + py) * kHW + (x0 + px);
#pragma unroll
  for (int a = 0; a < 64; ++a) {
    int c = (a >> 4) * 64 + cs * 16 + (a & 15);
    size_t off = pixbase + (size_t)c * (kHW * kHW);
    out[off] = acc[a] + x_low[off];
  }
}

// ---------------------------------------------------------------------------
// Final GN apply: bf16 conv output -> normalized fp32
// ---------------------------------------------------------------------------
__global__ __launch_bounds__(256) void gnapply_kernel(
    const u16* __restrict__ y, const float* __restrict__ stat,
    const float* __restrict__ gw, const float* __restrict__ gb, float* __restrict__ out)
{
  const int total = 4194304;  // 33.5M elems / 8
  for (int i8 = blockIdx.x * 256 + threadIdx.x; i8 < total; i8 += gridDim.x * 256) {
    size_t e0 = (size_t)i8 * 8;
    int c  = (int)((e0 >> 14) & 255);
    int b  = (int)(e0 >> 22);
    int bg = b * 32 + (c >> 3);
    float mean = stat[bg], rstd = stat[256 + bg];
    float A  = rstd * gw[c];
    float Bv = fmaf(-mean, A, gb[c]);
    int4 v = reinterpret_cast<const int4*>(y)[i8];
    float f[8]; unpack8(v, f);
    float4 o0 = make_float4(fmaf(f[0],A,Bv), fmaf(f[1],A,Bv), fmaf(f[2],A,Bv), fmaf(f[3],A,Bv));
    float4 o1 = make_float4(fmaf(f[4],A,Bv), fmaf(f[5],A,Bv), fmaf(f[6],A,Bv), fmaf(f[7],A,Bv));
    reinterpret_cast<float4*>(out)[(size_t)i8 * 2]     = o0;
    reinterpret_cast<float4*>(out)[(size_t)i8 * 2 + 1] = o1;
  }
}

// ---------------------------------------------------------------------------
extern "C" void kernel_launch(void* const* d_in, const int* in_sizes, int n_in,
                              void* d_out, int out_size, void* d_ws, size_t ws_size,
                              hipStream_t stream)
{
  const float* x_low  = (const float*)d_in[0];
  const float* x_high = (const float*)d_in[1];
  const float* w_q    = (const float*)d_in[2];
  const float* gq_w   = (const float*)d_in[3];
  const float* gq_b   = (const float*)d_in[4];
  const float* w_k    = (const float*)d_in[5];
  const float* gk_w   = (const float*)d_in[6];
  const float* gk_b   = (const float*)d_in[7];
  const float* w_o    = (const float*)d_in[8];
  const float* go_w   = (const float*)d_in[9];
  const float* go_b   = (const float*)d_in[10];
  float* out = (float*)d_out;

  // Workspace layout: yq bf16 (64MB) | yk bf16 (64MB) | stats (3 x 512 f32)
  char* ws = (char*)d_ws;
  u16*   yq    = (u16*)ws;
  u16*   yk    = (u16*)(ws + (size_t)67108864);
  float* statq = (float*)(ws + (size_t)134217728);
  float* statk = statq + 512;
  float* stato = statk + 512;

  dim3 cgrid(16, 16, 8);  // oc-tiles, y-tiles, batch
  conv3x3_kernel<<<cgrid, 256, 0, stream>>>(x_low,  w_q, yq);
  conv3x3_kernel<<<cgrid, 256, 0, stream>>>(x_high, w_k, yk);
  gnstats_kernel<<<256, 256, 0, stream>>>(yq, statq);
  gnstats_kernel<<<256, 256, 0, stream>>>(yk, statk);
  attn_kernel<<<2048, 256, 0, stream>>>(yq, yk, statq, statk,
                                        gq_w, gq_b, gk_w, gk_b, x_low, out);
  conv3x3_kernel<<<cgrid, 256, 0, stream>>>(out, w_o, yq);   // yq reused for y3
  gnstats_kernel<<<256, 256, 0, stream>>>(yq, stato);
  gnapply_kernel<<<4096, 256, 0, stream>>>(yq, stato, go_w, go_b, out);
}

// Round 2
// 1513.518 us; speedup vs baseline: 4.0723x; 4.0723x over previous
//
#include <hip/hip_runtime.h>

using u16 = unsigned short;
using u32 = unsigned int;

typedef short bfrag8 __attribute__((ext_vector_type(8)));   // 8 x bf16
typedef float f32x4  __attribute__((ext_vector_type(4)));

__device__ __forceinline__ void unpack8(const int4 v, float f[8]) {
  u32 a = (u32)v.x, b = (u32)v.y, c = (u32)v.z, d = (u32)v.w;
  f[0] = __uint_as_float(a << 16);
  f[1] = __uint_as_float(a & 0xffff0000u);
  f[2] = __uint_as_float(b << 16);
  f[3] = __uint_as_float(b & 0xffff0000u);
  f[4] = __uint_as_float(c << 16);
  f[5] = __uint_as_float(c & 0xffff0000u);
  f[6] = __uint_as_float(d << 16);
  f[7] = __uint_as_float(d & 0xffff0000u);
}

__device__ __forceinline__ u16 f2bf(float f) {
  u32 u = __float_as_uint(f);
  u32 r = u + 0x7fffu + ((u >> 16) & 1u);
  return (u16)(r >> 16);
}

__device__ __forceinline__ void gload_lds16(const void* g, void* l) {
  __builtin_amdgcn_global_load_lds(
      (const __attribute__((address_space(1))) void*)g,
      (__attribute__((address_space(3))) void*)l, 16, 0, 0);
}

// ---------------------------------------------------------------------------
// Weight prep: fp32 OIHW [256][256][3][3] -> bf16 [9 tap][256 oc][256 ic]
// ---------------------------------------------------------------------------
__global__ __launch_bounds__(256) void wprep(
    const float* __restrict__ wq, const float* __restrict__ wk, const float* __restrict__ wo,
    u16* __restrict__ dq, u16* __restrict__ dk, u16* __restrict__ dwo)
{
  const float* s = (blockIdx.y == 0) ? wq : (blockIdx.y == 1) ? wk : wo;
  u16* d = (blockIdx.y == 0) ? dq : (blockIdx.y == 1) ? dk : dwo;
  int id = blockIdx.x * 256 + threadIdx.x;
  int e = id * 4;                 // output element base: [tap][oc][ic]
  int tap = e >> 16;
  int rem = e & 65535;
  int oc = rem >> 8, ic = rem & 255;
  u16 o[4];
#pragma unroll
  for (int j = 0; j < 4; ++j)
    o[j] = f2bf(s[((size_t)oc * 256 + ic + j) * 9 + tap]);
  *reinterpret_cast<uint2*>(d + e) = *reinterpret_cast<uint2*>(o);
}

// ---------------------------------------------------------------------------
// Transpose-convert: fp32 NCHW -> bf16 NHWC (register transpose, no LDS)
// grid (128 row, 8 b, 2 which), 256 thr
// ---------------------------------------------------------------------------
__global__ __launch_bounds__(256) void xpose(
    const float* __restrict__ xa, const float* __restrict__ xb,
    u16* __restrict__ oa, u16* __restrict__ ob)
{
  const int row = blockIdx.x, b = blockIdx.y;
  const float* src = blockIdx.z ? xb : xa;
  u16* dst = blockIdx.z ? ob : oa;
  const int t = threadIdx.x;
  const int px4 = (t & 31) * 4;
  const int c8 = (t >> 5) * 8;
#pragma unroll
  for (int p = 0; p < 4; ++p) {
    int c0 = p * 64 + c8;
    float4 v[8];
#pragma unroll
    for (int j = 0; j < 8; ++j)
      v[j] = *reinterpret_cast<const float4*>(src + ((size_t)b * 256 + c0 + j) * 16384 + row * 128 + px4);
#pragma unroll
    for (int e = 0; e < 4; ++e) {
      u16 o[8];
      o[0] = f2bf(e==0?v[0].x:e==1?v[0].y:e==2?v[0].z:v[0].w);
      o[1] = f2bf(e==0?v[1].x:e==1?v[1].y:e==2?v[1].z:v[1].w);
      o[2] = f2bf(e==0?v[2].x:e==1?v[2].y:e==2?v[2].z:v[2].w);
      o[3] = f2bf(e==0?v[3].x:e==1?v[3].y:e==2?v[3].z:v[3].w);
      o[4] = f2bf(e==0?v[4].x:e==1?v[4].y:e==2?v[4].z:v[4].w);
      o[5] = f2bf(e==0?v[5].x:e==1?v[5].y:e==2?v[5].z:v[5].w);
      o[6] = f2bf(e==0?v[6].x:e==1?v[6].y:e==2?v[6].z:v[6].w);
      o[7] = f2bf(e==0?v[7].x:e==1?v[7].y:e==2?v[7].z:v[7].w);
      *reinterpret_cast<int4*>(dst + (((size_t)b * 128 + row) * 128 + px4 + e) * 256 + c0) =
          *reinterpret_cast<int4*>(o);
    }
  }
}

// ---------------------------------------------------------------------------
// Implicit-GEMM bf16 MFMA conv3x3. X: NHWC bf16, W2: [9][256][256] bf16,
// Y: NHWC bf16. Block: 128 oc x 128 px (one image row). 4 waves.
// LDS: Blds [kh][cidx 132][q4][8ic] (25344B), Alds dbuf [oc128][q4][8ic] (2x8192B)
// ---------------------------------------------------------------------------
__global__ __launch_bounds__(256, 3) void conv_mfma(
    const u16* __restrict__ X, const u16* __restrict__ W2, u16* __restrict__ Y)
{
  __shared__ __attribute__((aligned(16))) u16 Blds[3 * 132 * 4 * 8];
  __shared__ __attribute__((aligned(16))) u16 Alds[2 * 128 * 4 * 8];

  const int t = threadIdx.x;
  const int lane = t & 63;
  const int wv = t >> 6;
  const int oc0 = blockIdx.x * 128;
  const int y0 = blockIdx.y;
  const int bb = blockIdx.z;
  const int och = wv >> 1, pxh = wv & 1;
  const int lc = lane & 15, lq = lane >> 4;

  f32x4 acc[4][4];
#pragma unroll
  for (int m = 0; m < 4; ++m)
#pragma unroll
    for (int n = 0; n < 4; ++n) acc[m][n] = (f32x4){0.f, 0.f, 0.f, 0.f};

  int a_base[4], b_base[4];
#pragma unroll
  for (int m = 0; m < 4; ++m) a_base[m] = ((och * 64 + m * 16 + lc) * 4 + lq) * 16;
#pragma unroll
  for (int n = 0; n < 4; ++n) b_base[n] = (pxh * 64 + n * 16 + lc) * 64 + lq * 16;

  const size_t xplane = (size_t)bb * (128 * 128 * 256);

  // upfront zeros: halo columns (cidx 0,129) + out-of-range kh planes
  {
    int4 z = {0, 0, 0, 0};
    if (t < 24) {
      int q = t & 3, sel = (t >> 2) & 1, kh = t >> 3;
      int cidx = sel ? 129 : 0;
      *reinterpret_cast<int4*>((char*)Blds + ((kh * 132 + cidx) * 4 + q) * 16) = z;
    }
    if (y0 == 0)
      for (int s = t; s < 528; s += 256) *reinterpret_cast<int4*>((char*)Blds + s * 16) = z;
    if (y0 == 127)
      for (int s = t; s < 528; s += 256) *reinterpret_cast<int4*>((char*)Blds + 16896 + s * 16) = z;
  }

  auto stageA = [&](int tap, int buf, int ic0) {
#pragma unroll
    for (int i = 0; i < 2; ++i) {
      int idx = t + i * 256;
      const u16* src = W2 + (((size_t)(tap * 256 + oc0 + (idx >> 2))) << 8) + ic0 + (idx & 3) * 8;
      gload_lds16(src, (char*)Alds + buf * 8192 + (i * 256 + (t & ~63)) * 16);
    }
  };
  auto stageB = [&](int ic0) {
#pragma unroll
    for (int i = 0; i < 6; ++i) {
      int idx = t + i * 256;
      int kh = idx >> 9;
      int row = y0 - 1 + kh;
      if (row >= 0 && row < 128) {
        int px = (idx & 511) >> 2, q = idx & 3;
        const u16* src = X + xplane + (((size_t)(row * 128 + px)) << 8) + ic0 + q * 8;
        gload_lds16(src, (char*)Blds + 64 + kh * 256 + (i * 256 + (t & ~63)) * 16);
      }
    }
  };

  stageB(0);
  stageA(0, 0, 0);
  __syncthreads();

  for (int chunk = 0; chunk < 8; ++chunk) {
    const int ic0 = chunk * 32;
#pragma unroll
    for (int tap = 0; tap < 9; ++tap) {
      const int kh = tap / 3, kw = tap % 3, buf = tap & 1;
      if (tap < 8) stageA(tap + 1, buf ^ 1, ic0);
      bfrag8 af[4], xf[4];
#pragma unroll
      for (int m = 0; m < 4; ++m)
        af[m] = *reinterpret_cast<const bfrag8*>((const char*)Alds + buf * 8192 + a_base[m]);
#pragma unroll
      for (int n = 0; n < 4; ++n)
        xf[n] = *reinterpret_cast<const bfrag8*>((const char*)Blds + kh * 8448 + kw * 64 + b_base[n]);
#pragma unroll
      for (int m = 0; m < 4; ++m)
#pragma unroll
        for (int n = 0; n < 4; ++n)
          acc[m][n] = __builtin_amdgcn_mfma_f32_16x16x32_bf16(af[m], xf[n], acc[m][n], 0, 0, 0);
      __syncthreads();
    }
    if (chunk < 7) {
      stageB(ic0 + 32);
      stageA(0, 0, ic0 + 32);
      __syncthreads();
    }
  }

  // epilogue: D rows = oc (lq*4 + reg), cols = px (lc). 8B packed stores.
  const int ocw = oc0 + och * 64 + lq * 4;
  const int pxw = pxh * 64 + lc;
#pragma unroll
  for (int m = 0; m < 4; ++m)
#pragma unroll
    for (int n = 0; n < 4; ++n) {
      u32 lo = (u32)f2bf(acc[m][n][0]) | ((u32)f2bf(acc[m][n][1]) << 16);
      u32 hi = (u32)f2bf(acc[m][n][2]) | ((u32)f2bf(acc[m][n][3]) << 16);
      uint2 pk = {lo, hi};
      *reinterpret_cast<uint2*>(Y + xplane + (((size_t)(y0 * 128 + pxw + n * 16)) << 8) + ocw + m * 16) = pk;
    }
}

// ---------------------------------------------------------------------------
// GN stats stage 1: NHWC bf16 -> per-(b,chunk) channel partial sums
// grid (32 chunk, 8 b). part[((b*32+chunk)*256 + c)*2 + {0,1}]
// ---------------------------------------------------------------------------
__global__ __launch_bounds__(256) void gnstat1(const u16* __restrict__ Y, float* __restrict__ part)
{
  const int chunk = blockIdx.x, b = blockIdx.y;
  const int t = threadIdx.x;
  const int c8 = (t & 31) * 8;
  const int pr = t >> 5;
  float s[8], ss[8];
#pragma unroll
  for (int j = 0; j < 8; ++j) { s[j] = 0.f; ss[j] = 0.f; }
  for (int i = 0; i < 64; ++i) {
    int p = chunk * 512 + pr + i * 8;
    int4 v = *reinterpret_cast<const int4*>(Y + ((size_t)b * 16384 + p) * 256 + c8);
    float f[8]; unpack8(v, f);
#pragma unroll
    for (int j = 0; j < 8; ++j) { s[j] += f[j]; ss[j] = fmaf(f[j], f[j], ss[j]); }
  }
  __shared__ float L[8][256];
#pragma unroll
  for (int j = 0; j < 8; ++j) L[pr][c8 + j] = s[j];
  __syncthreads();
  float sv = 0.f;
#pragma unroll
  for (int r = 0; r < 8; ++r) sv += L[r][t];
  __syncthreads();
#pragma unroll
  for (int j = 0; j < 8; ++j) L[pr][c8 + j] = ss[j];
  __syncthreads();
  float ssv = 0.f;
#pragma unroll
  for (int r = 0; r < 8; ++r) ssv += L[r][t];
  part[(((size_t)b * 32 + chunk) * 256 + t) * 2 + 0] = sv;
  part[(((size_t)b * 32 + chunk) * 256 + t) * 2 + 1] = ssv;
}

// stage 2: reduce 32 chunks, fold 8 channels/group -> stat[b*32+g], stat[256+..]
__global__ __launch_bounds__(256) void gnstat2(const float* __restrict__ part, float* __restrict__ stat)
{
  const int b = blockIdx.x, t = threadIdx.x;
  float s = 0.f, ss = 0.f;
  for (int ch = 0; ch < 32; ++ch) {
    s  += part[(((size_t)b * 32 + ch) * 256 + t) * 2 + 0];
    ss += part[(((size_t)b * 32 + ch) * 256 + t) * 2 + 1];
  }
  __shared__ float Ls[256], Lss[256];
  Ls[t] = s; Lss[t] = ss;
  __syncthreads();
  if (t < 32) {
    float S = 0.f, SS = 0.f;
#pragma unroll
    for (int j = 0; j < 8; ++j) { S += Ls[t * 8 + j]; SS += Lss[t * 8 + j]; }
    float mean = S * (1.f / 131072.f);
    float var = SS * (1.f / 131072.f) - mean * mean;
    stat[b * 32 + t] = mean;
    stat[256 + b * 32 + t] = rsqrtf(var + 1e-5f);
  }
}

// ---------------------------------------------------------------------------
// Per-patch attention (NHWC bf16 in). Writes bf16 NHWC residual (attn + x_low).
// ---------------------------------------------------------------------------
__global__ __launch_bounds__(256) void attn_kernel(
    const u16* __restrict__ yq, const u16* __restrict__ yk,
    const float* __restrict__ statq, const float* __restrict__ statk,
    const float* __restrict__ gqw, const float* __restrict__ gqb,
    const float* __restrict__ gkw, const float* __restrict__ gkb,
    const float* __restrict__ x_low, u16* __restrict__ resid)
{
  __shared__ __attribute__((aligned(16))) float qch[64][72];
  __shared__ __attribute__((aligned(16))) float kch[64][72];
  __shared__ float P[64][65];

  const int n  = blockIdx.x;
  const int b  = n >> 8;
  const int ph = (n >> 4) & 15;
  const int pw = n & 15;
  const int y0 = ph * 8, x0 = pw * 8;
  const int t  = threadIdx.x;
  const int row_i = t >> 2, jq = t & 3;

  float S[16];
#pragma unroll
  for (int j = 0; j < 16; ++j) S[j] = 0.f;

  // ---- QK^T over 4 channel chunks ----
  for (int cc = 0; cc < 4; ++cc) {
    __syncthreads();
#pragma unroll
    for (int rr = 0; rr < 2; ++rr) {
      int r = t + rr * 256;
      int pixl = r >> 3, c8 = r & 7;
      int py = pixl >> 3, px = pixl & 7;
      size_t gp = (((size_t)b * 128 + y0 + py) * 128 + x0 + px) * 256 + cc * 64 + c8 * 8;
      int g = cc * 8 + c8;
      int cw = cc * 64 + c8 * 8;
      {
        float mean = statq[b * 32 + g], rstd = statq[256 + b * 32 + g];
        float4 w0 = *reinterpret_cast<const float4*>(gqw + cw);
        float4 w1 = *reinterpret_cast<const float4*>(gqw + cw + 4);
        float4 bq0 = *reinterpret_cast<const float4*>(gqb + cw);
        float4 bq1 = *reinterpret_cast<const float4*>(gqb + cw + 4);
        float ww[8] = {w0.x, w0.y, w0.z, w0.w, w1.x, w1.y, w1.z, w1.w};
        float bbv[8] = {bq0.x, bq0.y, bq0.z, bq0.w, bq1.x, bq1.y, bq1.z, bq1.w};
        int4 v = *reinterpret_cast<const int4*>(yq + gp);
        float f[8]; unpack8(v, f);
#pragma unroll
        for (int j = 0; j < 8; ++j) {
          float A = rstd * ww[j];
          qch[c8 * 8 + j][pixl] = fmaf(f[j], A, bbv[j] - mean * A);
        }
      }
      {
        float mean = statk[b * 32 + g], rstd = statk[256 + b * 32 + g];
        float4 w0 = *reinterpret_cast<const float4*>(gkw + cw);
        float4 w1 = *reinterpret_cast<const float4*>(gkw + cw + 4);
        float4 bk0 = *reinterpret_cast<const float4*>(gkb + cw);
        float4 bk1 = *reinterpret_cast<const float4*>(gkb + cw + 4);
        float ww[8] = {w0.x, w0.y, w0.z, w0.w, w1.x, w1.y, w1.z, w1.w};
        float bbv[8] = {bk0.x, bk0.y, bk0.z, bk0.w, bk1.x, bk1.y, bk1.z, bk1.w};
        int4 v = *reinterpret_cast<const int4*>(yk + gp);
        float f[8]; unpack8(v, f);
#pragma unroll
        for (int j = 0; j < 8; ++j) {
          float A = rstd * ww[j];
          kch[c8 * 8 + j][pixl] = fmaf(f[j], A, bbv[j] - mean * A);
        }
      }
    }
    __syncthreads();
#pragma unroll 4
    for (int c = 0; c < 64; ++c) {
      float qv = qch[c][row_i];
      const float* kr = &kch[c][jq * 16];
      float4 k0 = *reinterpret_cast<const float4*>(kr);
      float4 k1 = *reinterpret_cast<const float4*>(kr + 4);
      float4 k2 = *reinterpret_cast<const float4*>(kr + 8);
      float4 k3 = *reinterpret_cast<const float4*>(kr + 12);
      S[0]  = fmaf(qv, k0.x, S[0]);  S[1]  = fmaf(qv, k0.y, S[1]);
      S[2]  = fmaf(qv, k0.z, S[2]);  S[3]  = fmaf(qv, k0.w, S[3]);
      S[4]  = fmaf(qv, k1.x, S[4]);  S[5]  = fmaf(qv, k1.y, S[5]);
      S[6]  = fmaf(qv, k1.z, S[6]);  S[7]  = fmaf(qv, k1.w, S[7]);
      S[8]  = fmaf(qv, k2.x, S[8]);  S[9]  = fmaf(qv, k2.y, S[9]);
      S[10] = fmaf(qv, k2.z, S[10]); S[11] = fmaf(qv, k2.w, S[11]);
      S[12] = fmaf(qv, k3.x, S[12]); S[13] = fmaf(qv, k3.y, S[13]);
      S[14] = fmaf(qv, k3.z, S[14]); S[15] = fmaf(qv, k3.w, S[15]);
    }
  }

  // ---- softmax (4 lanes per row) ----
  float m = S[0];
#pragma unroll
  for (int j = 1; j < 16; ++j) m = fmaxf(m, S[j]);
  m = fmaxf(m, __shfl_xor(m, 1));
  m = fmaxf(m, __shfl_xor(m, 2));
  float sum = 0.f;
#pragma unroll
  for (int j = 0; j < 16; ++j) { S[j] = __expf((S[j] - m) * 0.0625f); sum += S[j]; }
  sum += __shfl_xor(sum, 1);
  sum += __shfl_xor(sum, 2);
  float inv = 1.f / sum;
#pragma unroll
  for (int j = 0; j < 16; ++j) P[row_i][jq * 16 + j] = S[j] * inv;

  // ---- PV ----
  const int i = t & 63;
  const int cs = t >> 6;
  float acc[64];
#pragma unroll
  for (int a = 0; a < 64; ++a) acc[a] = 0.f;

#pragma unroll
  for (int cc = 0; cc < 4; ++cc) {
    __syncthreads();
#pragma unroll
    for (int rr = 0; rr < 2; ++rr) {
      int r = t + rr * 256;
      int pixl = r >> 3, c8 = r & 7;
      int py = pixl >> 3, px = pixl & 7;
      size_t gp = (((size_t)b * 128 + y0 + py) * 128 + x0 + px) * 256 + cc * 64 + c8 * 8;
      int g = cc * 8 + c8;
      int cw = cc * 64 + c8 * 8;
      float mean = statk[b * 32 + g], rstd = statk[256 + b * 32 + g];
      float4 w0 = *reinterpret_cast<const float4*>(gkw + cw);
      float4 w1 = *reinterpret_cast<const float4*>(gkw + cw + 4);
      float4 bk0 = *reinterpret_cast<const float4*>(gkb + cw);
      float4 bk1 = *reinterpret_cast<const float4*>(gkb + cw + 4);
      float ww[8] = {w0.x, w0.y, w0.z, w0.w, w1.x, w1.y, w1.z, w1.w};
      float bbv[8] = {bk0.x, bk0.y, bk0.z, bk0.w, bk1.x, bk1.y, bk1.z, bk1.w};
      int4 v = *reinterpret_cast<const int4*>(yk + gp);
      float f[8]; unpack8(v, f);
#pragma unroll
      for (int j = 0; j < 8; ++j) {
        float A = rstd * ww[j];
        kch[c8 * 8 + j][pixl] = fmaf(f[j], A, bbv[j] - mean * A);
      }
    }
    __syncthreads();
#pragma unroll
    for (int q4 = 0; q4 < 4; ++q4) {
      float p[16];
#pragma unroll
      for (int jj = 0; jj < 16; ++jj) p[jj] = P[i][q4 * 16 + jj];
#pragma unroll
      for (int k = 0; k < 16; ++k) {
        const float* kr = &kch[cs * 16 + k][q4 * 16];
        float4 k0 = *reinterpret_cast<const float4*>(kr);
        float4 k1 = *reinterpret_cast<const float4*>(kr + 4);
        float4 k2 = *reinterpret_cast<const float4*>(kr + 8);
        float4 k3 = *reinterpret_cast<const float4*>(kr + 12);
        float s = acc[cc * 16 + k];
        s = fmaf(p[0],  k0.x, s); s = fmaf(p[1],  k0.y, s);
        s = fmaf(p[2],  k0.z, s); s = fmaf(p[3],  k0.w, s);
        s = fmaf(p[4],  k1.x, s); s = fmaf(p[5],  k1.y, s);
        s = fmaf(p[6],  k1.z, s); s = fmaf(p[7],  k1.w, s);
        s = fmaf(p[8],  k2.x, s); s = fmaf(p[9],  k2.y, s);
        s = fmaf(p[10], k2.z, s); s = fmaf(p[11], k2.w, s);
        s = fmaf(p[12], k3.x, s); s = fmaf(p[13], k3.y, s);
        s = fmaf(p[14], k3.z, s); s = fmaf(p[15], k3.w, s);
        acc[cc * 16 + k] = s;
      }
    }
  }

  // ---- residual add (x_low fp32 NCHW, coalesced per channel) + bf16 NHWC store
  const int py = i >> 3, px = i & 7;
  const size_t pixg = ((size_t)b * 128 + y0 + py) * 128 + (x0 + px);
  const float* xlb = x_low + (size_t)b * 256 * 16384 + (size_t)(y0 + py) * 128 + (x0 + px);
#pragma unroll
  for (int cc = 0; cc < 4; ++cc) {
    u16 ov[16];
#pragma unroll
    for (int k2 = 0; k2 < 16; ++k2) {
      int c = cc * 64 + cs * 16 + k2;
      float xv = xlb[(size_t)c * 16384];
      ov[k2] = f2bf(acc[cc * 16 + k2] + xv);
    }
    *reinterpret_cast<int4*>(resid + pixg * 256 + cc * 64 + cs * 16) =
        *reinterpret_cast<int4*>(&ov[0]);
    *reinterpret_cast<int4*>(resid + pixg * 256 + cc * 64 + cs * 16 + 8) =
        *reinterpret_cast<int4*>(&ov[8]);
  }
}

// ---------------------------------------------------------------------------
// Final GN apply + NHWC bf16 -> NCHW fp32 transpose (register transpose)
// grid (128 row, 8 b)
// ---------------------------------------------------------------------------
__global__ __launch_bounds__(256) void gnapply_t(
    const u16* __restrict__ Y, const float* __restrict__ stat,
    const float* __restrict__ gw, const float* __restrict__ gb,
    float* __restrict__ out)
{
  const int row = blockIdx.x, b = blockIdx.y;
  const int t = threadIdx.x;
  const int px4 = (t & 31) * 4;
  const int c8 = (t >> 5) * 8;
#pragma unroll
  for (int p = 0; p < 4; ++p) {
    int c0 = p * 64 + c8;
    int g = c0 >> 3;
    float mean = stat[b * 32 + g], rstd = stat[256 + b * 32 + g];
    float A[8], Bv[8];
#pragma unroll
    for (int j = 0; j < 8; ++j) {
      A[j] = rstd * gw[c0 + j];
      Bv[j] = gb[c0 + j] - mean * A[j];
    }
    float vals[4][8];
#pragma unroll
    for (int e = 0; e < 4; ++e) {
      int4 v = *reinterpret_cast<const int4*>(Y + (((size_t)b * 128 + row) * 128 + px4 + e) * 256 + c0);
      float f[8]; unpack8(v, f);
#pragma unroll
      for (int j = 0; j < 8; ++j) vals[e][j] = fmaf(f[j], A[j], Bv[j]);
    }
#pragma unroll
    for (int j = 0; j < 8; ++j) {
      float4 o = {vals[0][j], vals[1][j], vals[2][j], vals[3][j]};
      *reinterpret_cast<float4*>(out + ((size_t)b * 256 + c0 + j) * 16384 + row * 128 + px4) = o;
    }
  }
}

// ---------------------------------------------------------------------------
extern "C" void kernel_launch(void* const* d_in, const int* in_sizes, int n_in,
                              void* d_out, int out_size, void* d_ws, size_t ws_size,
                              hipStream_t stream)
{
  const float* x_low  = (const float*)d_in[0];
  const float* x_high = (const float*)d_in[1];
  const float* w_q    = (const float*)d_in[2];
  const float* gq_w   = (const float*)d_in[3];
  const float* gq_b   = (const float*)d_in[4];
  const float* w_k    = (const float*)d_in[5];
  const float* gk_w   = (const float*)d_in[6];
  const float* gk_b   = (const float*)d_in[7];
  const float* w_o    = (const float*)d_in[8];
  const float* go_w   = (const float*)d_in[9];
  const float* go_b   = (const float*)d_in[10];
  float* out = (float*)d_out;

  char* ws = (char*)d_ws;
  const size_t slot = 67108864;           // 33.55M bf16
  u16* xl = (u16*)(ws + 0 * slot);        // x_low bf16 NHWC ; later y3
  u16* xh = (u16*)(ws + 1 * slot);        // x_high bf16 NHWC ; later resid
  u16* yq = (u16*)(ws + 2 * slot);
  u16* yk = (u16*)(ws + 3 * slot);
  u16* W2q = (u16*)(ws + 4 * slot);
  u16* W2k = W2q + 589824;
  u16* W2o = W2k + 589824;
  float* partq = (float*)(ws + 4 * slot + 3 * 1179648);
  float* partk = partq + 131072;
  float* statq = partk + 131072;
  float* statk = statq + 512;
  float* stato = statk + 512;

  wprep<<<dim3(576, 3), 256, 0, stream>>>(w_q, w_k, w_o, W2q, W2k, W2o);
  xpose<<<dim3(128, 8, 2), 256, 0, stream>>>(x_low, x_high, xl, xh);
  conv_mfma<<<dim3(2, 128, 8), 256, 0, stream>>>(xl, W2q, yq);
  conv_mfma<<<dim3(2, 128, 8), 256, 0, stream>>>(xh, W2k, yk);
  gnstat1<<<dim3(32, 8), 256, 0, stream>>>(yq, partq);
  gnstat1<<<dim3(32, 8), 256, 0, stream>>>(yk, partk);
  gnstat2<<<8, 256, 0, stream>>>(partq, statq);
  gnstat2<<<8, 256, 0, stream>>>(partk, statk);
  attn_kernel<<<2048, 256, 0, stream>>>(yq, yk, statq, statk,
                                        gq_w, gq_b, gk_w, gk_b, x_low, xh);
  conv_mfma<<<dim3(2, 128, 8), 256, 0, stream>>>(xh, W2o, xl);
  gnstat1<<<dim3(32, 8), 256, 0, stream>>>(xl, partq);
  gnstat2<<<8, 256, 0, stream>>>(partq, stato);
  gnapply_t<<<dim3(128, 8), 256, 0, stream>>>(xl, stato, go_w, go_b, out);
}

// Round 3
// 1125.168 us; speedup vs baseline: 5.4779x; 1.3451x over previous
//
#include <hip/hip_runtime.h>

using u16 = unsigned short;
using u32 = unsigned int;

typedef short bfrag8 __attribute__((ext_vector_type(8)));   // 8 x bf16
typedef float f32x4  __attribute__((ext_vector_type(4)));

__device__ __forceinline__ void unpack8(const int4 v, float f[8]) {
  u32 a = (u32)v.x, b = (u32)v.y, c = (u32)v.z, d = (u32)v.w;
  f[0] = __uint_as_float(a << 16);
  f[1] = __uint_as_float(a & 0xffff0000u);
  f[2] = __uint_as_float(b << 16);
  f[3] = __uint_as_float(b & 0xffff0000u);
  f[4] = __uint_as_float(c << 16);
  f[5] = __uint_as_float(c & 0xffff0000u);
  f[6] = __uint_as_float(d << 16);
  f[7] = __uint_as_float(d & 0xffff0000u);
}

__device__ __forceinline__ u16 f2bf(float f) {
  u32 u = __float_as_uint(f);
  u32 r = u + 0x7fffu + ((u >> 16) & 1u);
  return (u16)(r >> 16);
}

__device__ __forceinline__ void gload_lds16(const void* g, void* l) {
  __builtin_amdgcn_global_load_lds(
      (const __attribute__((address_space(1))) void*)g,
      (__attribute__((address_space(3))) void*)l, 16, 0, 0);
}

// ---------------------------------------------------------------------------
// Weight prep: fp32 OIHW [256][256][3][3] -> bf16 [9 tap][256 oc][256 ic]
// ---------------------------------------------------------------------------
__global__ __launch_bounds__(256) void wprep(
    const float* __restrict__ wq, const float* __restrict__ wk, const float* __restrict__ wo,
    u16* __restrict__ dq, u16* __restrict__ dk, u16* __restrict__ dwo)
{
  const float* s = (blockIdx.y == 0) ? wq : (blockIdx.y == 1) ? wk : wo;
  u16* d = (blockIdx.y == 0) ? dq : (blockIdx.y == 1) ? dk : dwo;
  int id = blockIdx.x * 256 + threadIdx.x;
  int e = id * 4;                 // output element base: [tap][oc][ic]
  int tap = e >> 16;
  int rem = e & 65535;
  int oc = rem >> 8, ic = rem & 255;
  u16 o[4];
#pragma unroll
  for (int j = 0; j < 4; ++j)
    o[j] = f2bf(s[((size_t)oc * 256 + ic + j) * 9 + tap]);
  *reinterpret_cast<uint2*>(d + e) = *reinterpret_cast<uint2*>(o);
}

// ---------------------------------------------------------------------------
// Transpose-convert: fp32 NCHW -> bf16 NHWC. Lane map: 8 consecutive lanes
// cover 8 channel-octets -> 128B contiguous writes per 8-lane group.
// grid (128 row, 8 b, 2 which), 256 thr
// ---------------------------------------------------------------------------
__global__ __launch_bounds__(256) void xpose(
    const float* __restrict__ xa, const float* __restrict__ xb,
    u16* __restrict__ oa, u16* __restrict__ ob)
{
  const int row = blockIdx.x, b = blockIdx.y;
  const float* src = blockIdx.z ? xb : xa;
  u16* dst = blockIdx.z ? ob : oa;
  const int t = threadIdx.x;
  const int px4 = (t >> 3) * 4;     // 0..124
  const int c8 = (t & 7) * 8;       // 0..56
#pragma unroll
  for (int p = 0; p < 4; ++p) {
    int c0 = p * 64 + c8;
    float4 v[8];
#pragma unroll
    for (int j = 0; j < 8; ++j)
      v[j] = *reinterpret_cast<const float4*>(src + ((size_t)b * 256 + c0 + j) * 16384 + row * 128 + px4);
#pragma unroll
    for (int e = 0; e < 4; ++e) {
      u16 o[8];
      o[0] = f2bf(e==0?v[0].x:e==1?v[0].y:e==2?v[0].z:v[0].w);
      o[1] = f2bf(e==0?v[1].x:e==1?v[1].y:e==2?v[1].z:v[1].w);
      o[2] = f2bf(e==0?v[2].x:e==1?v[2].y:e==2?v[2].z:v[2].w);
      o[3] = f2bf(e==0?v[3].x:e==1?v[3].y:e==2?v[3].z:v[3].w);
      o[4] = f2bf(e==0?v[4].x:e==1?v[4].y:e==2?v[4].z:v[4].w);
      o[5] = f2bf(e==0?v[5].x:e==1?v[5].y:e==2?v[5].z:v[5].w);
      o[6] = f2bf(e==0?v[6].x:e==1?v[6].y:e==2?v[6].z:v[6].w);
      o[7] = f2bf(e==0?v[7].x:e==1?v[7].y:e==2?v[7].z:v[7].w);
      *reinterpret_cast<int4*>(dst + (((size_t)b * 128 + row) * 128 + px4 + e) * 256 + c0) =
          *reinterpret_cast<int4*>(o);
    }
  }
}

// ---------------------------------------------------------------------------
// Implicit-GEMM bf16 MFMA conv3x3. X: NHWC bf16, W2: [9][256][256] bf16,
// Y: NHWC bf16. Block: 128 oc x 128 px (one image row). 4 waves.
// Epilogue restaged through LDS for fully-coalesced 256B-run stores.
// ---------------------------------------------------------------------------
__global__ __launch_bounds__(256, 3) void conv_mfma(
    const u16* __restrict__ X, const u16* __restrict__ W2, u16* __restrict__ Y)
{
  __shared__ __attribute__((aligned(16))) char csm[41728];
  // Blds: [3 kh][132 cidx][4 q][8 ic] u16 = 25344B at csm+0
  // Alds: dbuf [2][128 oc][4 q][8 ic] u16 = 16384B at csm+25344
  // Ost (epilogue alias): [128 px][136] u16 = 34816B at csm+0

  const int t = threadIdx.x;
  const int lane = t & 63;
  const int wv = t >> 6;
  const int oc0 = blockIdx.x * 128;
  const int y0 = blockIdx.y;
  const int bb = blockIdx.z;
  const int och = wv >> 1, pxh = wv & 1;
  const int lc = lane & 15, lq = lane >> 4;

  f32x4 acc[4][4];
#pragma unroll
  for (int m = 0; m < 4; ++m)
#pragma unroll
    for (int n = 0; n < 4; ++n) acc[m][n] = (f32x4){0.f, 0.f, 0.f, 0.f};

  int a_base[4], b_base[4];
#pragma unroll
  for (int m = 0; m < 4; ++m) a_base[m] = 25344 + (((och * 64 + m * 16 + lc) * 4 + lq) * 16) * 2 / 2 * 2;
#pragma unroll
  for (int n = 0; n < 4; ++n) b_base[n] = (((pxh * 64 + n * 16 + lc) * 64 + lq * 16)) * 2;

  const size_t xplane = (size_t)bb * (128 * 128 * 256);

  // upfront zeros: halo columns (cidx 0,129) + out-of-range kh planes
  {
    int4 z = {0, 0, 0, 0};
    if (t < 24) {
      int q = t & 3, sel = (t >> 2) & 1, kh = t >> 3;
      int cidx = sel ? 129 : 0;
      *reinterpret_cast<int4*>(csm + ((kh * 132 + cidx) * 4 + q) * 16) = z;
    }
    if (y0 == 0)
      for (int s = t; s < 528; s += 256) *reinterpret_cast<int4*>(csm + s * 16) = z;
    if (y0 == 127)
      for (int s = t; s < 528; s += 256) *reinterpret_cast<int4*>(csm + 16896 + s * 16) = z;
  }

  auto stageA = [&](int tap, int buf, int ic0) {
#pragma unroll
    for (int i = 0; i < 2; ++i) {
      int idx = t + i * 256;
      const u16* src = W2 + (((size_t)(tap * 256 + oc0 + (idx >> 2))) << 8) + ic0 + (idx & 3) * 8;
      gload_lds16(src, csm + 25344 + buf * 8192 + (i * 256 + (t & ~63)) * 16);
    }
  };
  auto stageB = [&](int ic0) {
#pragma unroll
    for (int i = 0; i < 6; ++i) {
      int idx = t + i * 256;
      int kh = idx >> 9;
      int row = y0 - 1 + kh;
      if (row >= 0 && row < 128) {
        int px = (idx & 511) >> 2, q = idx & 3;
        const u16* src = X + xplane + (((size_t)(row * 128 + px)) << 8) + ic0 + q * 8;
        gload_lds16(src, csm + 64 + kh * 256 + (i * 256 + (t & ~63)) * 16);
      }
    }
  };

  stageB(0);
  stageA(0, 0, 0);
  __syncthreads();

  for (int chunk = 0; chunk < 8; ++chunk) {
    const int ic0 = chunk * 32;
#pragma unroll
    for (int tap = 0; tap < 9; ++tap) {
      const int kh = tap / 3, kw = tap % 3, buf = tap & 1;
      if (tap < 8) stageA(tap + 1, buf ^ 1, ic0);
      bfrag8 af[4], xf[4];
#pragma unroll
      for (int m = 0; m < 4; ++m)
        af[m] = *reinterpret_cast<const bfrag8*>(csm + 25344 + buf * 8192 +
                    ((och * 64 + m * 16 + lc) * 4 + lq) * 16);
#pragma unroll
      for (int n = 0; n < 4; ++n)
        xf[n] = *reinterpret_cast<const bfrag8*>(csm + kh * 8448 + kw * 64 +
                    ((pxh * 64 + n * 16 + lc) * 64 + lq * 16));
#pragma unroll
      for (int m = 0; m < 4; ++m)
#pragma unroll
        for (int n = 0; n < 4; ++n)
          acc[m][n] = __builtin_amdgcn_mfma_f32_16x16x32_bf16(af[m], xf[n], acc[m][n], 0, 0, 0);
      __syncthreads();
    }
    if (chunk < 7) {
      stageB(ic0 + 32);
      stageA(0, 0, ic0 + 32);
      __syncthreads();
    }
  }

  // epilogue: restage through LDS, then 256B-contiguous coalesced stores
  u16* Ost = (u16*)csm;                     // [128 px][136]
  const int chb = och * 64 + lq * 4;        // channel base within block (0..124)
  const int pxb = pxh * 64 + lc;            // pixel base (0..79 step)
#pragma unroll
  for (int m = 0; m < 4; ++m)
#pragma unroll
    for (int n = 0; n < 4; ++n) {
      u32 lo = (u32)f2bf(acc[m][n][0]) | ((u32)f2bf(acc[m][n][1]) << 16);
      u32 hi = (u32)f2bf(acc[m][n][2]) | ((u32)f2bf(acc[m][n][3]) << 16);
      uint2 pk = {lo, hi};
      *reinterpret_cast<uint2*>(&Ost[(pxb + n * 16) * 136 + chb + m * 16]) = pk;
    }
  __syncthreads();
#pragma unroll
  for (int s = 0; s < 8; ++s) {
    int pix = s * 16 + (t >> 4);
    int sub = t & 15;
    int4 v = *reinterpret_cast<const int4*>(&Ost[pix * 136 + sub * 8]);
    *reinterpret_cast<int4*>(Y + xplane + (((size_t)(y0 * 128 + pix)) << 8) + oc0 + sub * 8) = v;
  }
}

// ---------------------------------------------------------------------------
// GN stats stage 1: NHWC bf16 -> per-(b,chunk) channel partial sums
// ---------------------------------------------------------------------------
__global__ __launch_bounds__(256) void gnstat1(const u16* __restrict__ Y, float* __restrict__ part)
{
  const int chunk = blockIdx.x, b = blockIdx.y;
  const int t = threadIdx.x;
  const int c8 = (t & 31) * 8;
  const int pr = t >> 5;
  float s[8], ss[8];
#pragma unroll
  for (int j = 0; j < 8; ++j) { s[j] = 0.f; ss[j] = 0.f; }
  for (int i = 0; i < 64; ++i) {
    int p = chunk * 512 + pr + i * 8;
    int4 v = *reinterpret_cast<const int4*>(Y + ((size_t)b * 16384 + p) * 256 + c8);
    float f[8]; unpack8(v, f);
#pragma unroll
    for (int j = 0; j < 8; ++j) { s[j] += f[j]; ss[j] = fmaf(f[j], f[j], ss[j]); }
  }
  __shared__ float L[8][256];
#pragma unroll
  for (int j = 0; j < 8; ++j) L[pr][c8 + j] = s[j];
  __syncthreads();
  float sv = 0.f;
#pragma unroll
  for (int r = 0; r < 8; ++r) sv += L[r][t];
  __syncthreads();
#pragma unroll
  for (int j = 0; j < 8; ++j) L[pr][c8 + j] = ss[j];
  __syncthreads();
  float ssv = 0.f;
#pragma unroll
  for (int r = 0; r < 8; ++r) ssv += L[r][t];
  part[(((size_t)b * 32 + chunk) * 256 + t) * 2 + 0] = sv;
  part[(((size_t)b * 32 + chunk) * 256 + t) * 2 + 1] = ssv;
}

// stage 2: reduce 32 chunks, fold 8 channels/group -> stat[b*32+g], stat[256+..]
__global__ __launch_bounds__(256) void gnstat2(const float* __restrict__ part, float* __restrict__ stat)
{
  const int b = blockIdx.x, t = threadIdx.x;
  float s = 0.f, ss = 0.f;
  for (int ch = 0; ch < 32; ++ch) {
    s  += part[(((size_t)b * 32 + ch) * 256 + t) * 2 + 0];
    ss += part[(((size_t)b * 32 + ch) * 256 + t) * 2 + 1];
  }
  __shared__ float Ls[256], Lss[256];
  Ls[t] = s; Lss[t] = ss;
  __syncthreads();
  if (t < 32) {
    float S = 0.f, SS = 0.f;
#pragma unroll
    for (int j = 0; j < 8; ++j) { S += Ls[t * 8 + j]; SS += Lss[t * 8 + j]; }
    float mean = S * (1.f / 131072.f);
    float var = SS * (1.f / 131072.f) - mean * mean;
    stat[b * 32 + t] = mean;
    stat[256 + b * 32 + t] = rsqrtf(var + 1e-5f);
  }
}

// ---------------------------------------------------------------------------
// Per-patch attention (NHWC bf16 in). Residual from bf16 NHWC xl; output
// restaged through LDS for coalesced 4KB-row stores.
// ---------------------------------------------------------------------------
__global__ __launch_bounds__(256) void attn_kernel(
    const u16* __restrict__ yq, const u16* __restrict__ yk,
    const float* __restrict__ statq, const float* __restrict__ statk,
    const float* __restrict__ gqw, const float* __restrict__ gqb,
    const float* __restrict__ gkw, const float* __restrict__ gkb,
    const u16* __restrict__ xl, u16* __restrict__ resid)
{
  __shared__ __attribute__((aligned(16))) char smem[53504];
  float (*qch)[72] = reinterpret_cast<float(*)[72]>(smem);            // 18432B
  float (*kch)[72] = reinterpret_cast<float(*)[72]>(smem + 18432);    // 18432B
  float (*P)[65]   = reinterpret_cast<float(*)[65]>(smem + 36864);    // 16640B
  u16 (*Ost)[264]  = reinterpret_cast<u16(*)[264]>(smem);             // 33792B alias

  const int n  = blockIdx.x;
  const int b  = n >> 8;
  const int ph = (n >> 4) & 15;
  const int pw = n & 15;
  const int y0 = ph * 8, x0 = pw * 8;
  const int t  = threadIdx.x;
  const int row_i = t >> 2, jq = t & 3;

  float S[16];
#pragma unroll
  for (int j = 0; j < 16; ++j) S[j] = 0.f;

  // ---- QK^T over 4 channel chunks ----
  for (int cc = 0; cc < 4; ++cc) {
    __syncthreads();
#pragma unroll
    for (int rr = 0; rr < 2; ++rr) {
      int r = t + rr * 256;
      int pixl = r >> 3, c8 = r & 7;
      int py = pixl >> 3, px = pixl & 7;
      size_t gp = (((size_t)b * 128 + y0 + py) * 128 + x0 + px) * 256 + cc * 64 + c8 * 8;
      int g = cc * 8 + c8;
      int cw = cc * 64 + c8 * 8;
      {
        float mean = statq[b * 32 + g], rstd = statq[256 + b * 32 + g];
        float4 w0 = *reinterpret_cast<const float4*>(gqw + cw);
        float4 w1 = *reinterpret_cast<const float4*>(gqw + cw + 4);
        float4 bq0 = *reinterpret_cast<const float4*>(gqb + cw);
        float4 bq1 = *reinterpret_cast<const float4*>(gqb + cw + 4);
        float ww[8] = {w0.x, w0.y, w0.z, w0.w, w1.x, w1.y, w1.z, w1.w};
        float bbv[8] = {bq0.x, bq0.y, bq0.z, bq0.w, bq1.x, bq1.y, bq1.z, bq1.w};
        int4 v = *reinterpret_cast<const int4*>(yq + gp);
        float f[8]; unpack8(v, f);
#pragma unroll
        for (int j = 0; j < 8; ++j) {
          float A = rstd * ww[j];
          qch[c8 * 8 + j][pixl] = fmaf(f[j], A, bbv[j] - mean * A);
        }
      }
      {
        float mean = statk[b * 32 + g], rstd = statk[256 + b * 32 + g];
        float4 w0 = *reinterpret_cast<const float4*>(gkw + cw);
        float4 w1 = *reinterpret_cast<const float4*>(gkw + cw + 4);
        float4 bk0 = *reinterpret_cast<const float4*>(gkb + cw);
        float4 bk1 = *reinterpret_cast<const float4*>(gkb + cw + 4);
        float ww[8] = {w0.x, w0.y, w0.z, w0.w, w1.x, w1.y, w1.z, w1.w};
        float bbv[8] = {bk0.x, bk0.y, bk0.z, bk0.w, bk1.x, bk1.y, bk1.z, bk1.w};
        int4 v = *reinterpret_cast<const int4*>(yk + gp);
        float f[8]; unpack8(v, f);
#pragma unroll
        for (int j = 0; j < 8; ++j) {
          float A = rstd * ww[j];
          kch[c8 * 8 + j][pixl] = fmaf(f[j], A, bbv[j] - mean * A);
        }
      }
    }
    __syncthreads();
#pragma unroll 4
    for (int c = 0; c < 64; ++c) {
      float qv = qch[c][row_i];
      const float* kr = &kch[c][jq * 16];
      float4 k0 = *reinterpret_cast<const float4*>(kr);
      float4 k1 = *reinterpret_cast<const float4*>(kr + 4);
      float4 k2 = *reinterpret_cast<const float4*>(kr + 8);
      float4 k3 = *reinterpret_cast<const float4*>(kr + 12);
      S[0]  = fmaf(qv, k0.x, S[0]);  S[1]  = fmaf(qv, k0.y, S[1]);
      S[2]  = fmaf(qv, k0.z, S[2]);  S[3]  = fmaf(qv, k0.w, S[3]);
      S[4]  = fmaf(qv, k1.x, S[4]);  S[5]  = fmaf(qv, k1.y, S[5]);
      S[6]  = fmaf(qv, k1.z, S[6]);  S[7]  = fmaf(qv, k1.w, S[7]);
      S[8]  = fmaf(qv, k2.x, S[8]);  S[9]  = fmaf(qv, k2.y, S[9]);
      S[10] = fmaf(qv, k2.z, S[10]); S[11] = fmaf(qv, k2.w, S[11]);
      S[12] = fmaf(qv, k3.x, S[12]); S[13] = fmaf(qv, k3.y, S[13]);
      S[14] = fmaf(qv, k3.z, S[14]); S[15] = fmaf(qv, k3.w, S[15]);
    }
  }

  // ---- softmax (4 lanes per row) ----
  float m = S[0];
#pragma unroll
  for (int j = 1; j < 16; ++j) m = fmaxf(m, S[j]);
  m = fmaxf(m, __shfl_xor(m, 1));
  m = fmaxf(m, __shfl_xor(m, 2));
  float sum = 0.f;
#pragma unroll
  for (int j = 0; j < 16; ++j) { S[j] = __expf((S[j] - m) * 0.0625f); sum += S[j]; }
  sum += __shfl_xor(sum, 1);
  sum += __shfl_xor(sum, 2);
  float inv = 1.f / sum;
#pragma unroll
  for (int j = 0; j < 16; ++j) P[row_i][jq * 16 + j] = S[j] * inv;

  // ---- PV ----
  const int i = t & 63;
  const int cs = t >> 6;
  float acc[64];
#pragma unroll
  for (int a = 0; a < 64; ++a) acc[a] = 0.f;

#pragma unroll
  for (int cc = 0; cc < 4; ++cc) {
    __syncthreads();
#pragma unroll
    for (int rr = 0; rr < 2; ++rr) {
      int r = t + rr * 256;
      int pixl = r >> 3, c8 = r & 7;
      int py = pixl >> 3, px = pixl & 7;
      size_t gp = (((size_t)b * 128 + y0 + py) * 128 + x0 + px) * 256 + cc * 64 + c8 * 8;
      int g = cc * 8 + c8;
      int cw = cc * 64 + c8 * 8;
      float mean = statk[b * 32 + g], rstd = statk[256 + b * 32 + g];
      float4 w0 = *reinterpret_cast<const float4*>(gkw + cw);
      float4 w1 = *reinterpret_cast<const float4*>(gkw + cw + 4);
      float4 bk0 = *reinterpret_cast<const float4*>(gkb + cw);
      float4 bk1 = *reinterpret_cast<const float4*>(gkb + cw + 4);
      float ww[8] = {w0.x, w0.y, w0.z, w0.w, w1.x, w1.y, w1.z, w1.w};
      float bbv[8] = {bk0.x, bk0.y, bk0.z, bk0.w, bk1.x, bk1.y, bk1.z, bk1.w};
      int4 v = *reinterpret_cast<const int4*>(yk + gp);
      float f[8]; unpack8(v, f);
#pragma unroll
      for (int j = 0; j < 8; ++j) {
        float A = rstd * ww[j];
        kch[c8 * 8 + j][pixl] = fmaf(f[j], A, bbv[j] - mean * A);
      }
    }
    __syncthreads();
#pragma unroll
    for (int q4 = 0; q4 < 4; ++q4) {
      float p[16];
#pragma unroll
      for (int jj = 0; jj < 16; ++jj) p[jj] = P[i][q4 * 16 + jj];
#pragma unroll
      for (int k = 0; k < 16; ++k) {
        const float* kr = &kch[cs * 16 + k][q4 * 16];
        float4 k0 = *reinterpret_cast<const float4*>(kr);
        float4 k1 = *reinterpret_cast<const float4*>(kr + 4);
        float4 k2 = *reinterpret_cast<const float4*>(kr + 8);
        float4 k3 = *reinterpret_cast<const float4*>(kr + 12);
        float s = acc[cc * 16 + k];
        s = fmaf(p[0],  k0.x, s); s = fmaf(p[1],  k0.y, s);
        s = fmaf(p[2],  k0.z, s); s = fmaf(p[3],  k0.w, s);
        s = fmaf(p[4],  k1.x, s); s = fmaf(p[5],  k1.y, s);
        s = fmaf(p[6],  k1.z, s); s = fmaf(p[7],  k1.w, s);
        s = fmaf(p[8],  k2.x, s); s = fmaf(p[9],  k2.y, s);
        s = fmaf(p[10], k2.z, s); s = fmaf(p[11], k2.w, s);
        s = fmaf(p[12], k3.x, s); s = fmaf(p[13], k3.y, s);
        s = fmaf(p[14], k3.z, s); s = fmaf(p[15], k3.w, s);
        acc[cc * 16 + k] = s;
      }
    }
  }

  // ---- epilogue: acc -> LDS (bf16), then coalesced residual+store ----
  __syncthreads();                       // everyone done reading kch/P
#pragma unroll
  for (int cc = 0; cc < 4; ++cc) {
    u16 ov[16];
#pragma unroll
    for (int k2 = 0; k2 < 16; ++k2) ov[k2] = f2bf(acc[cc * 16 + k2]);
    int col = cc * 64 + cs * 16;
    *reinterpret_cast<int4*>(&Ost[i][col])     = *reinterpret_cast<int4*>(&ov[0]);
    *reinterpret_cast<int4*>(&Ost[i][col + 8]) = *reinterpret_cast<int4*>(&ov[8]);
  }
  __syncthreads();
#pragma unroll
  for (int s = 0; s < 8; ++s) {
    int px = t >> 5;                     // 0..7
    int c16 = t & 31;                    // 16B channel segment
    size_t g = (((size_t)b * 128 + y0 + s) * 128 + x0 + px) * 256 + c16 * 8;
    int4 o = *reinterpret_cast<const int4*>(&Ost[s * 8 + px][c16 * 8]);
    int4 r = *reinterpret_cast<const int4*>(xl + g);
    float fo[8], fr[8]; unpack8(o, fo); unpack8(r, fr);
    u16 pk[8];
#pragma unroll
    for (int j = 0; j < 8; ++j) pk[j] = f2bf(fo[j] + fr[j]);
    *reinterpret_cast<int4*>(resid + g) = *reinterpret_cast<int4*>(pk);
  }
}

// ---------------------------------------------------------------------------
// Final GN apply + NHWC bf16 -> NCHW fp32 transpose (register transpose)
// ---------------------------------------------------------------------------
__global__ __launch_bounds__(256) void gnapply_t(
    const u16* __restrict__ Y, const float* __restrict__ stat,
    const float* __restrict__ gw, const float* __restrict__ gb,
    float* __restrict__ out)
{
  const int row = blockIdx.x, b = blockIdx.y;
  const int t = threadIdx.x;
  const int px4 = (t & 31) * 4;
  const int c8 = (t >> 5) * 8;
#pragma unroll
  for (int p = 0; p < 4; ++p) {
    int c0 = p * 64 + c8;
    int g = c0 >> 3;
    float mean = stat[b * 32 + g], rstd = stat[256 + b * 32 + g];
    float A[8], Bv[8];
#pragma unroll
    for (int j = 0; j < 8; ++j) {
      A[j] = rstd * gw[c0 + j];
      Bv[j] = gb[c0 + j] - mean * A[j];
    }
    float vals[4][8];
#pragma unroll
    for (int e = 0; e < 4; ++e) {
      int4 v = *reinterpret_cast<const int4*>(Y + (((size_t)b * 128 + row) * 128 + px4 + e) * 256 + c0);
      float f[8]; unpack8(v, f);
#pragma unroll
      for (int j = 0; j < 8; ++j) vals[e][j] = fmaf(f[j], A[j], Bv[j]);
    }
#pragma unroll
    for (int j = 0; j < 8; ++j) {
      float4 o = {vals[0][j], vals[1][j], vals[2][j], vals[3][j]};
      *reinterpret_cast<float4*>(out + ((size_t)b * 256 + c0 + j) * 16384 + row * 128 + px4) = o;
    }
  }
}

// ---------------------------------------------------------------------------
extern "C" void kernel_launch(void* const* d_in, const int* in_sizes, int n_in,
                              void* d_out, int out_size, void* d_ws, size_t ws_size,
                              hipStream_t stream)
{
  const float* x_low  = (const float*)d_in[0];
  const float* x_high = (const float*)d_in[1];
  const float* w_q    = (const float*)d_in[2];
  const float* gq_w   = (const float*)d_in[3];
  const float* gq_b   = (const float*)d_in[4];
  const float* w_k    = (const float*)d_in[5];
  const float* gk_w   = (const float*)d_in[6];
  const float* gk_b   = (const float*)d_in[7];
  const float* w_o    = (const float*)d_in[8];
  const float* go_w   = (const float*)d_in[9];
  const float* go_b   = (const float*)d_in[10];
  float* out = (float*)d_out;

  char* ws = (char*)d_ws;
  const size_t slot = 67108864;           // 33.55M bf16
  u16* xl = (u16*)(ws + 0 * slot);        // x_low bf16 NHWC ; later y3
  u16* xh = (u16*)(ws + 1 * slot);        // x_high bf16 NHWC ; later resid
  u16* yq = (u16*)(ws + 2 * slot);
  u16* yk = (u16*)(ws + 3 * slot);
  u16* W2q = (u16*)(ws + 4 * slot);
  u16* W2k = W2q + 589824;
  u16* W2o = W2k + 589824;
  float* partq = (float*)(ws + 4 * slot + 3 * 1179648);
  float* partk = partq + 131072;
  float* statq = partk + 131072;
  float* statk = statq + 512;
  float* stato = statk + 512;

  wprep<<<dim3(576, 3), 256, 0, stream>>>(w_q, w_k, w_o, W2q, W2k, W2o);
  xpose<<<dim3(128, 8, 2), 256, 0, stream>>>(x_low, x_high, xl, xh);
  conv_mfma<<<dim3(2, 128, 8), 256, 0, stream>>>(xl, W2q, yq);
  conv_mfma<<<dim3(2, 128, 8), 256, 0, stream>>>(xh, W2k, yk);
  gnstat1<<<dim3(32, 8), 256, 0, stream>>>(yq, partq);
  gnstat1<<<dim3(32, 8), 256, 0, stream>>>(yk, partk);
  gnstat2<<<8, 256, 0, stream>>>(partq, statq);
  gnstat2<<<8, 256, 0, stream>>>(partk, statk);
  attn_kernel<<<2048, 256, 0, stream>>>(yq, yk, statq, statk,
                                        gq_w, gq_b, gk_w, gk_b, xl, xh);
  conv_mfma<<<dim3(2, 128, 8), 256, 0, stream>>>(xh, W2o, xl);
  gnstat1<<<dim3(32, 8), 256, 0, stream>>>(xl, partq);
  gnstat2<<<8, 256, 0, stream>>>(partq, stato);
  gnapply_t<<<dim3(128, 8), 256, 0, stream>>>(xl, stato, go_w, go_b, out);
}

// Round 4
// 798.141 us; speedup vs baseline: 7.7224x; 1.4097x over previous
//
#include <hip/hip_runtime.h>

using u16 = unsigned short;
using u32 = unsigned int;

typedef short bfrag8 __attribute__((ext_vector_type(8)));   // 8 x bf16
typedef float f32x4  __attribute__((ext_vector_type(4)));

__device__ __forceinline__ void unpack8(const int4 v, float f[8]) {
  u32 a = (u32)v.x, b = (u32)v.y, c = (u32)v.z, d = (u32)v.w;
  f[0] = __uint_as_float(a << 16);
  f[1] = __uint_as_float(a & 0xffff0000u);
  f[2] = __uint_as_float(b << 16);
  f[3] = __uint_as_float(b & 0xffff0000u);
  f[4] = __uint_as_float(c << 16);
  f[5] = __uint_as_float(c & 0xffff0000u);
  f[6] = __uint_as_float(d << 16);
  f[7] = __uint_as_float(d & 0xffff0000u);
}

__device__ __forceinline__ u16 f2bf(float f) {
  u32 u = __float_as_uint(f);
  u32 r = u + 0x7fffu + ((u >> 16) & 1u);
  return (u16)(r >> 16);
}

__device__ __forceinline__ void gload_lds16(const void* g, void* l) {
  __builtin_amdgcn_global_load_lds(
      (const __attribute__((address_space(1))) void*)g,
      (__attribute__((address_space(3))) void*)l, 16, 0, 0);
}

// ---------------------------------------------------------------------------
// Weight prep: fp32 OIHW [256][256][3][3] -> bf16 [9 tap][256 oc][256 ic]
// ---------------------------------------------------------------------------
__global__ __launch_bounds__(256) void wprep(
    const float* __restrict__ wq, const float* __restrict__ wk, const float* __restrict__ wo,
    u16* __restrict__ dq, u16* __restrict__ dk, u16* __restrict__ dwo)
{
  const float* s = (blockIdx.y == 0) ? wq : (blockIdx.y == 1) ? wk : wo;
  u16* d = (blockIdx.y == 0) ? dq : (blockIdx.y == 1) ? dk : dwo;
  int id = blockIdx.x * 256 + threadIdx.x;
  int e = id * 4;                 // output element base: [tap][oc][ic]
  int tap = e >> 16;
  int rem = e & 65535;
  int oc = rem >> 8, ic = rem & 255;
  u16 o[4];
#pragma unroll
  for (int j = 0; j < 4; ++j)
    o[j] = f2bf(s[((size_t)oc * 256 + ic + j) * 9 + tap]);
  *reinterpret_cast<uint2*>(d + e) = *reinterpret_cast<uint2*>(o);
}

// ---------------------------------------------------------------------------
// Transpose-convert: fp32 NCHW -> bf16 NHWC.
// ---------------------------------------------------------------------------
__global__ __launch_bounds__(256) void xpose(
    const float* __restrict__ xa, const float* __restrict__ xb,
    u16* __restrict__ oa, u16* __restrict__ ob)
{
  const int row = blockIdx.x, b = blockIdx.y;
  const float* src = blockIdx.z ? xb : xa;
  u16* dst = blockIdx.z ? ob : oa;
  const int t = threadIdx.x;
  const int px4 = (t >> 3) * 4;     // 0..124
  const int c8 = (t & 7) * 8;       // 0..56
#pragma unroll
  for (int p = 0; p < 4; ++p) {
    int c0 = p * 64 + c8;
    float4 v[8];
#pragma unroll
    for (int j = 0; j < 8; ++j)
      v[j] = *reinterpret_cast<const float4*>(src + ((size_t)b * 256 + c0 + j) * 16384 + row * 128 + px4);
#pragma unroll
    for (int e = 0; e < 4; ++e) {
      u16 o[8];
      o[0] = f2bf(e==0?v[0].x:e==1?v[0].y:e==2?v[0].z:v[0].w);
      o[1] = f2bf(e==0?v[1].x:e==1?v[1].y:e==2?v[1].z:v[1].w);
      o[2] = f2bf(e==0?v[2].x:e==1?v[2].y:e==2?v[2].z:v[2].w);
      o[3] = f2bf(e==0?v[3].x:e==1?v[3].y:e==2?v[3].z:v[3].w);
      o[4] = f2bf(e==0?v[4].x:e==1?v[4].y:e==2?v[4].z:v[4].w);
      o[5] = f2bf(e==0?v[5].x:e==1?v[5].y:e==2?v[5].z:v[5].w);
      o[6] = f2bf(e==0?v[6].x:e==1?v[6].y:e==2?v[6].z:v[6].w);
      o[7] = f2bf(e==0?v[7].x:e==1?v[7].y:e==2?v[7].z:v[7].w);
      *reinterpret_cast<int4*>(dst + (((size_t)b * 128 + row) * 128 + px4 + e) * 256 + c0) =
          *reinterpret_cast<int4*>(o);
    }
  }
}

// ---------------------------------------------------------------------------
// Implicit-GEMM bf16 MFMA conv3x3 (unchanged from R3).
// ---------------------------------------------------------------------------
__global__ __launch_bounds__(256, 3) void conv_mfma(
    const u16* __restrict__ X, const u16* __restrict__ W2, u16* __restrict__ Y)
{
  __shared__ __attribute__((aligned(16))) char csm[41728];

  const int t = threadIdx.x;
  const int lane = t & 63;
  const int wv = t >> 6;
  const int oc0 = blockIdx.x * 128;
  const int y0 = blockIdx.y;
  const int bb = blockIdx.z;
  const int och = wv >> 1, pxh = wv & 1;
  const int lc = lane & 15, lq = lane >> 4;

  f32x4 acc[4][4];
#pragma unroll
  for (int m = 0; m < 4; ++m)
#pragma unroll
    for (int n = 0; n < 4; ++n) acc[m][n] = (f32x4){0.f, 0.f, 0.f, 0.f};

  const size_t xplane = (size_t)bb * (128 * 128 * 256);

  {
    int4 z = {0, 0, 0, 0};
    if (t < 24) {
      int q = t & 3, sel = (t >> 2) & 1, kh = t >> 3;
      int cidx = sel ? 129 : 0;
      *reinterpret_cast<int4*>(csm + ((kh * 132 + cidx) * 4 + q) * 16) = z;
    }
    if (y0 == 0)
      for (int s = t; s < 528; s += 256) *reinterpret_cast<int4*>(csm + s * 16) = z;
    if (y0 == 127)
      for (int s = t; s < 528; s += 256) *reinterpret_cast<int4*>(csm + 16896 + s * 16) = z;
  }

  auto stageA = [&](int tap, int buf, int ic0) {
#pragma unroll
    for (int i = 0; i < 2; ++i) {
      int idx = t + i * 256;
      const u16* src = W2 + (((size_t)(tap * 256 + oc0 + (idx >> 2))) << 8) + ic0 + (idx & 3) * 8;
      gload_lds16(src, csm + 25344 + buf * 8192 + (i * 256 + (t & ~63)) * 16);
    }
  };
  auto stageB = [&](int ic0) {
#pragma unroll
    for (int i = 0; i < 6; ++i) {
      int idx = t + i * 256;
      int kh = idx >> 9;
      int row = y0 - 1 + kh;
      if (row >= 0 && row < 128) {
        int px = (idx & 511) >> 2, q = idx & 3;
        const u16* src = X + xplane + (((size_t)(row * 128 + px)) << 8) + ic0 + q * 8;
        gload_lds16(src, csm + 64 + kh * 256 + (i * 256 + (t & ~63)) * 16);
      }
    }
  };

  stageB(0);
  stageA(0, 0, 0);
  __syncthreads();

  for (int chunk = 0; chunk < 8; ++chunk) {
    const int ic0 = chunk * 32;
#pragma unroll
    for (int tap = 0; tap < 9; ++tap) {
      const int kh = tap / 3, kw = tap % 3, buf = tap & 1;
      if (tap < 8) stageA(tap + 1, buf ^ 1, ic0);
      bfrag8 af[4], xf[4];
#pragma unroll
      for (int m = 0; m < 4; ++m)
        af[m] = *reinterpret_cast<const bfrag8*>(csm + 25344 + buf * 8192 +
                    ((och * 64 + m * 16 + lc) * 4 + lq) * 16);
#pragma unroll
      for (int n = 0; n < 4; ++n)
        xf[n] = *reinterpret_cast<const bfrag8*>(csm + kh * 8448 + kw * 64 +
                    ((pxh * 64 + n * 16 + lc) * 64 + lq * 16));
#pragma unroll
      for (int m = 0; m < 4; ++m)
#pragma unroll
        for (int n = 0; n < 4; ++n)
          acc[m][n] = __builtin_amdgcn_mfma_f32_16x16x32_bf16(af[m], xf[n], acc[m][n], 0, 0, 0);
      __syncthreads();
    }
    if (chunk < 7) {
      stageB(ic0 + 32);
      stageA(0, 0, ic0 + 32);
      __syncthreads();
    }
  }

  u16* Ost = (u16*)csm;                     // [128 px][136]
  const int chb = och * 64 + lq * 4;
  const int pxb = pxh * 64 + lc;
#pragma unroll
  for (int m = 0; m < 4; ++m)
#pragma unroll
    for (int n = 0; n < 4; ++n) {
      u32 lo = (u32)f2bf(acc[m][n][0]) | ((u32)f2bf(acc[m][n][1]) << 16);
      u32 hi = (u32)f2bf(acc[m][n][2]) | ((u32)f2bf(acc[m][n][3]) << 16);
      uint2 pk = {lo, hi};
      *reinterpret_cast<uint2*>(&Ost[(pxb + n * 16) * 136 + chb + m * 16]) = pk;
    }
  __syncthreads();
#pragma unroll
  for (int s = 0; s < 8; ++s) {
    int pix = s * 16 + (t >> 4);
    int sub = t & 15;
    int4 v = *reinterpret_cast<const int4*>(&Ost[pix * 136 + sub * 8]);
    *reinterpret_cast<int4*>(Y + xplane + (((size_t)(y0 * 128 + pix)) << 8) + oc0 + sub * 8) = v;
  }
}

// ---------------------------------------------------------------------------
// GN stats stage 1 + 2 (unchanged)
// ---------------------------------------------------------------------------
__global__ __launch_bounds__(256) void gnstat1(const u16* __restrict__ Y, float* __restrict__ part)
{
  const int chunk = blockIdx.x, b = blockIdx.y;
  const int t = threadIdx.x;
  const int c8 = (t & 31) * 8;
  const int pr = t >> 5;
  float s[8], ss[8];
#pragma unroll
  for (int j = 0; j < 8; ++j) { s[j] = 0.f; ss[j] = 0.f; }
  for (int i = 0; i < 64; ++i) {
    int p = chunk * 512 + pr + i * 8;
    int4 v = *reinterpret_cast<const int4*>(Y + ((size_t)b * 16384 + p) * 256 + c8);
    float f[8]; unpack8(v, f);
#pragma unroll
    for (int j = 0; j < 8; ++j) { s[j] += f[j]; ss[j] = fmaf(f[j], f[j], ss[j]); }
  }
  __shared__ float L[8][256];
#pragma unroll
  for (int j = 0; j < 8; ++j) L[pr][c8 + j] = s[j];
  __syncthreads();
  float sv = 0.f;
#pragma unroll
  for (int r = 0; r < 8; ++r) sv += L[r][t];
  __syncthreads();
#pragma unroll
  for (int j = 0; j < 8; ++j) L[pr][c8 + j] = ss[j];
  __syncthreads();
  float ssv = 0.f;
#pragma unroll
  for (int r = 0; r < 8; ++r) ssv += L[r][t];
  part[(((size_t)b * 32 + chunk) * 256 + t) * 2 + 0] = sv;
  part[(((size_t)b * 32 + chunk) * 256 + t) * 2 + 1] = ssv;
}

__global__ __launch_bounds__(256) void gnstat2(const float* __restrict__ part, float* __restrict__ stat)
{
  const int b = blockIdx.x, t = threadIdx.x;
  float s = 0.f, ss = 0.f;
  for (int ch = 0; ch < 32; ++ch) {
    s  += part[(((size_t)b * 32 + ch) * 256 + t) * 2 + 0];
    ss += part[(((size_t)b * 32 + ch) * 256 + t) * 2 + 1];
  }
  __shared__ float Ls[256], Lss[256];
  Ls[t] = s; Lss[t] = ss;
  __syncthreads();
  if (t < 32) {
    float S = 0.f, SS = 0.f;
#pragma unroll
    for (int j = 0; j < 8; ++j) { S += Ls[t * 8 + j]; SS += Lss[t * 8 + j]; }
    float mean = S * (1.f / 131072.f);
    float var = SS * (1.f / 131072.f) - mean * mean;
    stat[b * 32 + t] = mean;
    stat[256 + b * 32 + t] = rsqrtf(var + 1e-5f);
  }
}

// ---------------------------------------------------------------------------
// normq: yq -> in-place q~ = (Aq*yq + Bq) * Ak   (folds GN(q) and k's scale;
// the Bk rank-1 term is row-constant in S and cancels in softmax)
// ---------------------------------------------------------------------------
__global__ __launch_bounds__(256) void normq(
    u16* __restrict__ yq, const float* __restrict__ statq, const float* __restrict__ statk,
    const float* __restrict__ gqw, const float* __restrict__ gqb, const float* __restrict__ gkw)
{
  const int row = blockIdx.x, b = blockIdx.y;
  const int t = threadIdx.x;
#pragma unroll
  for (int i = 0; i < 16; ++i) {
    int idx = i * 256 + t;
    int c8 = (idx & 31) * 8;
    int g = c8 >> 3;
    float meanq = statq[b * 32 + g], rstdq = statq[256 + b * 32 + g];
    float rstdk = statk[256 + b * 32 + g];
    size_t off = (((size_t)b * 128 + row) * 128 + (idx >> 5)) * 256 + c8;
    int4 v = *reinterpret_cast<const int4*>(yq + off);
    float f[8]; unpack8(v, f);
    u16 o[8];
#pragma unroll
    for (int j = 0; j < 8; ++j) {
      float Aq = rstdq * gqw[c8 + j];
      float Bq = gqb[c8 + j] - meanq * Aq;
      float Ak = rstdk * gkw[c8 + j];
      o[j] = f2bf((f[j] * Aq + Bq) * Ak);
    }
    *reinterpret_cast<int4*>(yq + off) = *reinterpret_cast<int4*>(o);
  }
}

// ---------------------------------------------------------------------------
// normkT: yk (raw NHWC) -> kT = GN(k) in layout [b][ph][py][pw][c][px]
// (conv-row region so attn PV B-fragments are 16B-contiguous, coalesced)
// ---------------------------------------------------------------------------
__global__ __launch_bounds__(256) void normkT(
    const u16* __restrict__ yk, const float* __restrict__ statk,
    const float* __restrict__ gkw, const float* __restrict__ gkb,
    u16* __restrict__ kT)
{
  __shared__ u16 L[8][264];
  const int y = blockIdx.x, b = blockIdx.y;   // y = ph*8+py
  const int ph = y >> 3, py = y & 7;
  const int t = threadIdx.x;
  const int px = t >> 5, c8 = (t & 31) * 8;
  const int g = c8 >> 3;
  float mean = statk[b * 32 + g], rstd = statk[256 + b * 32 + g];
  float A[8], Bv[8];
#pragma unroll
  for (int j = 0; j < 8; ++j) {
    A[j] = rstd * gkw[c8 + j];
    Bv[j] = gkb[c8 + j] - mean * A[j];
  }
  const size_t rowbase = (((size_t)b * 128 + y) * 128) * 256;
  const size_t outbase = ((size_t)(b * 16 + ph) * 8 + py) * 32768;
  for (int pw = 0; pw < 16; ++pw) {
    int4 v = *reinterpret_cast<const int4*>(yk + rowbase + (size_t)(pw * 8 + px) * 256 + c8);
    float f[8]; unpack8(v, f);
    u16 o[8];
#pragma unroll
    for (int j = 0; j < 8; ++j) o[j] = f2bf(f[j] * A[j] + Bv[j]);
    *reinterpret_cast<int4*>(&L[px][c8]) = *reinterpret_cast<int4*>(o);
    __syncthreads();
    u16 o2[8];
#pragma unroll
    for (int q = 0; q < 8; ++q) o2[q] = L[q][t];
    *reinterpret_cast<int4*>(kT + outbase + (size_t)(pw * 256 + t) * 8) = *reinterpret_cast<int4*>(o2);
    __syncthreads();
  }
}

// ---------------------------------------------------------------------------
// MFMA attention. One block per patch, 4 waves; wave w owns query rows
// 16w..16w+15. QK^T: A = q~ (NHWC frags), B = raw yk (NHWC frags).
// Softmax in registers (shfl_xor over 16-lane groups). P -> per-wave LDS
// strip. PV: A = P strip, B = kT frags. Epilogue: LDS restage + residual.
// ---------------------------------------------------------------------------
#define OST 280
__global__ __launch_bounds__(256, 3) void attn_mfma(
    const u16* __restrict__ qt, const u16* __restrict__ yk,
    const u16* __restrict__ kT, const u16* __restrict__ xl,
    u16* __restrict__ resid)
{
  __shared__ __attribute__((aligned(16))) u16 smem[64 * OST + 4 * 16 * 72];
  u16* Ost = smem;                       // [64][OST]
  u16* Pls = smem + 64 * OST;            // 4 x [16][72]

  const int n = blockIdx.x;
  const int b = n >> 8, ph = (n >> 4) & 15, pw = n & 15;
  const int t = threadIdx.x, l = t & 63, w = t >> 6;
  const int lc = l & 15, lg = l >> 4;

  auto tokaddr = [&](int tok) -> size_t {
    return (((size_t)(b * 128 + ph * 8 + (tok >> 3))) * 128 + pw * 8 + (tok & 7)) * 256;
  };

  // ---- QK^T ----
  const size_t qa = tokaddr(16 * w + lc) + lg * 8;
  bfrag8 aF[8];
#pragma unroll
  for (int ks = 0; ks < 8; ++ks)
    aF[ks] = *reinterpret_cast<const bfrag8*>(qt + qa + ks * 32);

  f32x4 sacc[4];
#pragma unroll
  for (int nt = 0; nt < 4; ++nt) sacc[nt] = (f32x4){0.f, 0.f, 0.f, 0.f};

#pragma unroll
  for (int nt = 0; nt < 4; ++nt) {
    const size_t ka = tokaddr(nt * 16 + lc) + lg * 8;
    bfrag8 bF[8];
#pragma unroll
    for (int ks = 0; ks < 8; ++ks)
      bF[ks] = *reinterpret_cast<const bfrag8*>(yk + ka + ks * 32);
#pragma unroll
    for (int ks = 0; ks < 8; ++ks)
      sacc[nt] = __builtin_amdgcn_mfma_f32_16x16x32_bf16(aF[ks], bF[ks], sacc[nt], 0, 0, 0);
  }

  // ---- softmax over j; scale 1/sqrt(256) = 1/16 ----
  u16* Pw = Pls + w * (16 * 72);
#pragma unroll
  for (int r = 0; r < 4; ++r) {
    float m0 = fmaxf(fmaxf(sacc[0][r], sacc[1][r]), fmaxf(sacc[2][r], sacc[3][r]));
    m0 = fmaxf(m0, __shfl_xor(m0, 1));
    m0 = fmaxf(m0, __shfl_xor(m0, 2));
    m0 = fmaxf(m0, __shfl_xor(m0, 4));
    m0 = fmaxf(m0, __shfl_xor(m0, 8));
    float p0 = __expf((sacc[0][r] - m0) * 0.0625f);
    float p1 = __expf((sacc[1][r] - m0) * 0.0625f);
    float p2 = __expf((sacc[2][r] - m0) * 0.0625f);
    float p3 = __expf((sacc[3][r] - m0) * 0.0625f);
    float s0 = p0 + p1 + p2 + p3;
    s0 += __shfl_xor(s0, 1);
    s0 += __shfl_xor(s0, 2);
    s0 += __shfl_xor(s0, 4);
    s0 += __shfl_xor(s0, 8);
    float inv = 1.f / s0;
    int prow = (lg * 4 + r) * 72;
    Pw[prow + 0 * 16 + lc] = f2bf(p0 * inv);
    Pw[prow + 1 * 16 + lc] = f2bf(p1 * inv);
    Pw[prow + 2 * 16 + lc] = f2bf(p2 * inv);
    Pw[prow + 3 * 16 + lc] = f2bf(p3 * inv);
  }

  // ---- PV: O = P * kN  (B-frags from kT, 16B contiguous) ----
  bfrag8 pA[2];
#pragma unroll
  for (int js = 0; js < 2; ++js)
    pA[js] = *reinterpret_cast<const bfrag8*>(Pw + lc * 72 + js * 32 + lg * 8);

  f32x4 pacc[16];
#pragma unroll
  for (int ct = 0; ct < 16; ++ct) pacc[ct] = (f32x4){0.f, 0.f, 0.f, 0.f};

#pragma unroll
  for (int ct = 0; ct < 16; ++ct) {
    bfrag8 vB[2];
#pragma unroll
    for (int js = 0; js < 2; ++js)
      vB[js] = *reinterpret_cast<const bfrag8*>(
          kT + ((size_t)((b * 16 + ph) * 8 + js * 4 + lg)) * 32768 +
          (size_t)(pw * 256 + ct * 16 + lc) * 8);
#pragma unroll
    for (int js = 0; js < 2; ++js)
      pacc[ct] = __builtin_amdgcn_mfma_f32_16x16x32_bf16(pA[js], vB[js], pacc[ct], 0, 0, 0);
  }

  // ---- epilogue: O -> LDS, then coalesced residual + store ----
#pragma unroll
  for (int ct = 0; ct < 16; ++ct)
#pragma unroll
    for (int r = 0; r < 4; ++r)
      Ost[(16 * w + lg * 4 + r) * OST + ct * 16 + lc] = f2bf(pacc[ct][r]);
  __syncthreads();

#pragma unroll
  for (int s = 0; s < 8; ++s) {
    int px_ = t >> 5;
    int c16 = t & 31;
    size_t g = (((size_t)b * 128 + ph * 8 + s) * 128 + pw * 8 + px_) * 256 + c16 * 8;
    int4 o = *reinterpret_cast<const int4*>(&Ost[(s * 8 + px_) * OST + c16 * 8]);
    int4 r = *reinterpret_cast<const int4*>(xl + g);
    float fo[8], fr[8]; unpack8(o, fo); unpack8(r, fr);
    u16 pk[8];
#pragma unroll
    for (int j = 0; j < 8; ++j) pk[j] = f2bf(fo[j] + fr[j]);
    *reinterpret_cast<int4*>(resid + g) = *reinterpret_cast<int4*>(pk);
  }
}

// ---------------------------------------------------------------------------
// Final GN apply + NHWC bf16 -> NCHW fp32 transpose
// ---------------------------------------------------------------------------
__global__ __launch_bounds__(256) void gnapply_t(
    const u16* __restrict__ Y, const float* __restrict__ stat,
    const float* __restrict__ gw, const float* __restrict__ gb,
    float* __restrict__ out)
{
  const int row = blockIdx.x, b = blockIdx.y;
  const int t = threadIdx.x;
  const int px4 = (t & 31) * 4;
  const int c8 = (t >> 5) * 8;
#pragma unroll
  for (int p = 0; p < 4; ++p) {
    int c0 = p * 64 + c8;
    int g = c0 >> 3;
    float mean = stat[b * 32 + g], rstd = stat[256 + b * 32 + g];
    float A[8], Bv[8];
#pragma unroll
    for (int j = 0; j < 8; ++j) {
      A[j] = rstd * gw[c0 + j];
      Bv[j] = gb[c0 + j] - mean * A[j];
    }
    float vals[4][8];
#pragma unroll
    for (int e = 0; e < 4; ++e) {
      int4 v = *reinterpret_cast<const int4*>(Y + (((size_t)b * 128 + row) * 128 + px4 + e) * 256 + c0);
      float f[8]; unpack8(v, f);
#pragma unroll
      for (int j = 0; j < 8; ++j) vals[e][j] = fmaf(f[j], A[j], Bv[j]);
    }
#pragma unroll
    for (int j = 0; j < 8; ++j) {
      float4 o = {vals[0][j], vals[1][j], vals[2][j], vals[3][j]};
      *reinterpret_cast<float4*>(out + ((size_t)b * 256 + c0 + j) * 16384 + row * 128 + px4) = o;
    }
  }
}

// ---------------------------------------------------------------------------
extern "C" void kernel_launch(void* const* d_in, const int* in_sizes, int n_in,
                              void* d_out, int out_size, void* d_ws, size_t ws_size,
                              hipStream_t stream)
{
  const float* x_low  = (const float*)d_in[0];
  const float* x_high = (const float*)d_in[1];
  const float* w_q    = (const float*)d_in[2];
  const float* gq_w   = (const float*)d_in[3];
  const float* gq_b   = (const float*)d_in[4];
  const float* w_k    = (const float*)d_in[5];
  const float* gk_w   = (const float*)d_in[6];
  const float* gk_b   = (const float*)d_in[7];
  const float* w_o    = (const float*)d_in[8];
  const float* go_w   = (const float*)d_in[9];
  const float* go_b   = (const float*)d_in[10];
  float* out = (float*)d_out;

  char* ws = (char*)d_ws;
  const size_t slot = 67108864;           // 33.55M bf16
  u16* xl  = (u16*)(ws + 0 * slot);       // x_low bf16 NHWC ; later y3
  u16* xh  = (u16*)(ws + 1 * slot);       // x_high bf16 NHWC ; later resid
  u16* yq  = (u16*)(ws + 2 * slot);       // q conv out; normq rewrites in-place
  u16* yk  = (u16*)(ws + 3 * slot);       // k conv out (raw, QK^T B operand)
  u16* kT  = (u16*)(ws + 4 * slot);       // normalized k, patch-transposed
  u16* W2q = (u16*)(ws + 5 * slot);
  u16* W2k = W2q + 589824;
  u16* W2o = W2k + 589824;
  float* partq = (float*)(ws + 5 * slot + 3 * 1179648);
  float* partk = partq + 131072;
  float* statq = partk + 131072;
  float* statk = statq + 512;
  float* stato = statk + 512;

  wprep<<<dim3(576, 3), 256, 0, stream>>>(w_q, w_k, w_o, W2q, W2k, W2o);
  xpose<<<dim3(128, 8, 2), 256, 0, stream>>>(x_low, x_high, xl, xh);
  conv_mfma<<<dim3(2, 128, 8), 256, 0, stream>>>(xl, W2q, yq);
  conv_mfma<<<dim3(2, 128, 8), 256, 0, stream>>>(xh, W2k, yk);
  gnstat1<<<dim3(32, 8), 256, 0, stream>>>(yq, partq);
  gnstat1<<<dim3(32, 8), 256, 0, stream>>>(yk, partk);
  gnstat2<<<8, 256, 0, stream>>>(partq, statq);
  gnstat2<<<8, 256, 0, stream>>>(partk, statk);
  normq<<<dim3(128, 8), 256, 0, stream>>>(yq, statq, statk, gq_w, gq_b, gk_w);
  normkT<<<dim3(128, 8), 256, 0, stream>>>(yk, statk, gk_w, gk_b, kT);
  attn_mfma<<<2048, 256, 0, stream>>>(yq, yk, kT, xl, xh);
  conv_mfma<<<dim3(2, 128, 8), 256, 0, stream>>>(xh, W2o, xl);
  gnstat1<<<dim3(32, 8), 256, 0, stream>>>(xl, partq);
  gnstat2<<<8, 256, 0, stream>>>(partq, stato);
  gnapply_t<<<dim3(128, 8), 256, 0, stream>>>(xl, stato, go_w, go_b, out);
}

// Round 5
// 693.703 us; speedup vs baseline: 8.8850x; 1.1506x over previous
//
#include <hip/hip_runtime.h>

using u16 = unsigned short;
using u32 = unsigned int;

typedef short bfrag8 __attribute__((ext_vector_type(8)));   // 8 x bf16
typedef float f32x4  __attribute__((ext_vector_type(4)));

__device__ __forceinline__ void unpack8(const int4 v, float f[8]) {
  u32 a = (u32)v.x, b = (u32)v.y, c = (u32)v.z, d = (u32)v.w;
  f[0] = __uint_as_float(a << 16);
  f[1] = __uint_as_float(a & 0xffff0000u);
  f[2] = __uint_as_float(b << 16);
  f[3] = __uint_as_float(b & 0xffff0000u);
  f[4] = __uint_as_float(c << 16);
  f[5] = __uint_as_float(c & 0xffff0000u);
  f[6] = __uint_as_float(d << 16);
  f[7] = __uint_as_float(d & 0xffff0000u);
}

__device__ __forceinline__ u16 f2bf(float f) {
  u32 u = __float_as_uint(f);
  u32 r = u + 0x7fffu + ((u >> 16) & 1u);
  return (u16)(r >> 16);
}

__device__ __forceinline__ void gload_lds16(const void* g, void* l) {
  __builtin_amdgcn_global_load_lds(
      (const __attribute__((address_space(1))) void*)g,
      (__attribute__((address_space(3))) void*)l, 16, 0, 0);
}

// ---------------------------------------------------------------------------
// Weight prep: fp32 OIHW [256][256][3][3] -> bf16 [9 tap][256 oc][256 ic]
// ---------------------------------------------------------------------------
__global__ __launch_bounds__(256) void wprep(
    const float* __restrict__ wq, const float* __restrict__ wk, const float* __restrict__ wo,
    u16* __restrict__ dq, u16* __restrict__ dk, u16* __restrict__ dwo)
{
  const float* s = (blockIdx.y == 0) ? wq : (blockIdx.y == 1) ? wk : wo;
  u16* d = (blockIdx.y == 0) ? dq : (blockIdx.y == 1) ? dk : dwo;
  int id = blockIdx.x * 256 + threadIdx.x;
  int e = id * 4;                 // output element base: [tap][oc][ic]
  int tap = e >> 16;
  int rem = e & 65535;
  int oc = rem >> 8, ic = rem & 255;
  u16 o[4];
#pragma unroll
  for (int j = 0; j < 4; ++j)
    o[j] = f2bf(s[((size_t)oc * 256 + ic + j) * 9 + tap]);
  *reinterpret_cast<uint2*>(d + e) = *reinterpret_cast<uint2*>(o);
}

// ---------------------------------------------------------------------------
// Transpose-convert: fp32 NCHW -> bf16 NHWC.
// ---------------------------------------------------------------------------
__global__ __launch_bounds__(256) void xpose(
    const float* __restrict__ xa, const float* __restrict__ xb,
    u16* __restrict__ oa, u16* __restrict__ ob)
{
  const int row = blockIdx.x, b = blockIdx.y;
  const float* src = blockIdx.z ? xb : xa;
  u16* dst = blockIdx.z ? ob : oa;
  const int t = threadIdx.x;
  const int px4 = (t >> 3) * 4;     // 0..124
  const int c8 = (t & 7) * 8;       // 0..56
#pragma unroll
  for (int p = 0; p < 4; ++p) {
    int c0 = p * 64 + c8;
    float4 v[8];
#pragma unroll
    for (int j = 0; j < 8; ++j)
      v[j] = *reinterpret_cast<const float4*>(src + ((size_t)b * 256 + c0 + j) * 16384 + row * 128 + px4);
#pragma unroll
    for (int e = 0; e < 4; ++e) {
      u16 o[8];
      o[0] = f2bf(e==0?v[0].x:e==1?v[0].y:e==2?v[0].z:v[0].w);
      o[1] = f2bf(e==0?v[1].x:e==1?v[1].y:e==2?v[1].z:v[1].w);
      o[2] = f2bf(e==0?v[2].x:e==1?v[2].y:e==2?v[2].z:v[2].w);
      o[3] = f2bf(e==0?v[3].x:e==1?v[3].y:e==2?v[3].z:v[3].w);
      o[4] = f2bf(e==0?v[4].x:e==1?v[4].y:e==2?v[4].z:v[4].w);
      o[5] = f2bf(e==0?v[5].x:e==1?v[5].y:e==2?v[5].z:v[5].w);
      o[6] = f2bf(e==0?v[6].x:e==1?v[6].y:e==2?v[6].z:v[6].w);
      o[7] = f2bf(e==0?v[7].x:e==1?v[7].y:e==2?v[7].z:v[7].w);
      *reinterpret_cast<int4*>(dst + (((size_t)b * 128 + row) * 128 + px4 + e) * 256 + c0) =
          *reinterpret_cast<int4*>(o);
    }
  }
}

// ---------------------------------------------------------------------------
// Implicit-GEMM bf16 MFMA conv3x3. 512 thr, 8 waves. Block: 256 oc x 128 px
// (one image row). XCD-chunked swizzle: each XCD owns one image -> halo and
// weight re-reads hit per-XCD L2. Fused GN partial stats from fp32 acc.
// LDS: Blds [3][132][4][8]u16 (25344) | Alds 2x[256][4][8]u16 (32768)
// epilogue alias: Ost [128][264]u16 (67584) + sst 2x2x256 f32 (4096) = 71680
// ---------------------------------------------------------------------------
__global__ __launch_bounds__(512, 4) void conv_mfma(
    const u16* __restrict__ X, const u16* __restrict__ W2, u16* __restrict__ Y,
    float* __restrict__ part)
{
  __shared__ __attribute__((aligned(16))) char csm[71680];

  const int t = threadIdx.x;
  const int l = t & 63;
  const int wv = t >> 6;
  const int id = blockIdx.x;
  const int u = (id & 7) * 128 + (id >> 3);   // XCD-chunk swizzle (bijective)
  const int bb = u >> 7, y0 = u & 127;
  const int och = wv >> 1, pxh = wv & 1;
  const int lc = l & 15, lq = l >> 4;

  f32x4 acc[4][4];
#pragma unroll
  for (int m = 0; m < 4; ++m)
#pragma unroll
    for (int n = 0; n < 4; ++n) acc[m][n] = (f32x4){0.f, 0.f, 0.f, 0.f};

  const size_t xplane = (size_t)bb * (128 * 128 * 256);

  // upfront zeros: halo columns (cidx 0,129) + out-of-range kh planes
  {
    int4 z = {0, 0, 0, 0};
    if (t < 24) {
      int q = t & 3, sel = (t >> 2) & 1, kh = t >> 3;
      int cidx = sel ? 129 : 0;
      *reinterpret_cast<int4*>(csm + ((kh * 132 + cidx) * 4 + q) * 16) = z;
    }
    if (y0 == 0)
      for (int s = t; s < 528; s += 512) *reinterpret_cast<int4*>(csm + s * 16) = z;
    if (y0 == 127)
      for (int s = t; s < 528; s += 512) *reinterpret_cast<int4*>(csm + 16896 + s * 16) = z;
  }

  auto stageA = [&](int tap, int buf, int ic0) {
#pragma unroll
    for (int i = 0; i < 2; ++i) {
      int idx = t + i * 512;
      const u16* src = W2 + (((size_t)(tap * 256 + (idx >> 2))) << 8) + ic0 + (idx & 3) * 8;
      gload_lds16(src, csm + 25344 + buf * 16384 + (i * 512 + (t & ~63)) * 16);
    }
  };
  auto stageB = [&](int ic0) {
#pragma unroll
    for (int i = 0; i < 3; ++i) {
      int idx = t + i * 512;
      int kh = idx >> 9;
      int row = y0 - 1 + kh;
      if (row >= 0 && row < 128) {
        int px = (idx & 511) >> 2, q = idx & 3;
        const u16* src = X + xplane + (((size_t)(row * 128 + px)) << 8) + ic0 + q * 8;
        gload_lds16(src, csm + 64 + kh * 256 + (i * 512 + (t & ~63)) * 16);
      }
    }
  };

  stageB(0);
  stageA(0, 0, 0);
  __syncthreads();

  for (int chunk = 0; chunk < 8; ++chunk) {
    const int ic0 = chunk * 32;
#pragma unroll
    for (int tap = 0; tap < 9; ++tap) {
      const int kh = tap / 3, kw = tap % 3, buf = tap & 1;
      if (tap < 8) stageA(tap + 1, buf ^ 1, ic0);
      bfrag8 af[4], xf[4];
#pragma unroll
      for (int m = 0; m < 4; ++m)
        af[m] = *reinterpret_cast<const bfrag8*>(csm + 25344 + buf * 16384 +
                    ((och * 64 + m * 16 + lc) * 4 + lq) * 16);
#pragma unroll
      for (int n = 0; n < 4; ++n)
        xf[n] = *reinterpret_cast<const bfrag8*>(csm + kh * 8448 + kw * 64 +
                    ((pxh * 64 + n * 16 + lc) * 64 + lq * 16));
#pragma unroll
      for (int m = 0; m < 4; ++m)
#pragma unroll
        for (int n = 0; n < 4; ++n)
          acc[m][n] = __builtin_amdgcn_mfma_f32_16x16x32_bf16(af[m], xf[n], acc[m][n], 0, 0, 0);
      __syncthreads();
    }
    if (chunk < 7) {
      stageB(ic0 + 32);
      stageA(0, 0, ic0 + 32);
      __syncthreads();
    }
  }

  // ---- epilogue: acc -> Ost (bf16) + per-channel stat partials ----
  u16* Ost = (u16*)csm;                       // [128 px][264]
  float* sst = (float*)(csm + 67584);         // [2 pxh][2 s/ss][256 c]
  const int chb = och * 64 + lq * 4;
  const int pxb = pxh * 64 + lc;
#pragma unroll
  for (int m = 0; m < 4; ++m)
#pragma unroll
    for (int n = 0; n < 4; ++n) {
      u32 lo = (u32)f2bf(acc[m][n][0]) | ((u32)f2bf(acc[m][n][1]) << 16);
      u32 hi = (u32)f2bf(acc[m][n][2]) | ((u32)f2bf(acc[m][n][3]) << 16);
      uint2 pk = {lo, hi};
      *reinterpret_cast<uint2*>(&Ost[(pxb + n * 16) * 264 + chb + m * 16]) = pk;
    }
#pragma unroll
  for (int m = 0; m < 4; ++m)
#pragma unroll
    for (int r = 0; r < 4; ++r) {
      float s  = acc[m][0][r] + acc[m][1][r] + acc[m][2][r] + acc[m][3][r];
      float ss = acc[m][0][r] * acc[m][0][r] + acc[m][1][r] * acc[m][1][r] +
                 acc[m][2][r] * acc[m][2][r] + acc[m][3][r] * acc[m][3][r];
#pragma unroll
      for (int off = 1; off < 16; off <<= 1) {
        s  += __shfl_xor(s, off);
        ss += __shfl_xor(ss, off);
      }
      if (lc == 0) {
        int c = och * 64 + m * 16 + lq * 4 + r;
        sst[pxh * 512 + c]       = s;
        sst[pxh * 512 + 256 + c] = ss;
      }
    }
  __syncthreads();

  if (t < 256) {
    float s  = sst[t]       + sst[512 + t];
    float ss = sst[256 + t] + sst[768 + t];
    size_t pb = (((size_t)bb * 128 + y0) * 256 + t) * 2;
    part[pb]     = s;
    part[pb + 1] = ss;
  }
#pragma unroll
  for (int s8 = 0; s8 < 8; ++s8) {
    int pix = s8 * 16 + (t >> 5);
    int sub = t & 31;
    int4 v = *reinterpret_cast<const int4*>(&Ost[pix * 264 + sub * 8]);
    *reinterpret_cast<int4*>(Y + xplane + (((size_t)(y0 * 128 + pix)) << 8) + sub * 8) = v;
  }
}

// ---------------------------------------------------------------------------
// Reduce conv's per-row stat partials -> stat[b*32+g] (mean), [256+..] (rstd)
// ---------------------------------------------------------------------------
__global__ __launch_bounds__(256) void gnstat2b(const float* __restrict__ part, float* __restrict__ stat)
{
  const int b = blockIdx.x, t = threadIdx.x;
  float s = 0.f, ss = 0.f;
  for (int row = 0; row < 128; ++row) {
    size_t pb = (((size_t)b * 128 + row) * 256 + t) * 2;
    s  += part[pb];
    ss += part[pb + 1];
  }
  __shared__ float Ls[256], Lss[256];
  Ls[t] = s; Lss[t] = ss;
  __syncthreads();
  if (t < 32) {
    float S = 0.f, SS = 0.f;
#pragma unroll
    for (int j = 0; j < 8; ++j) { S += Ls[t * 8 + j]; SS += Lss[t * 8 + j]; }
    float mean = S * (1.f / 131072.f);
    float var = SS * (1.f / 131072.f) - mean * mean;
    stat[b * 32 + t] = mean;
    stat[256 + b * 32 + t] = rsqrtf(var + 1e-5f);
  }
}

// ---------------------------------------------------------------------------
// normkT: yk (raw NHWC) -> kT = GN(k) in layout [b][ph][py][pw][c][px]
// ---------------------------------------------------------------------------
__global__ __launch_bounds__(256) void normkT(
    const u16* __restrict__ yk, const float* __restrict__ statk,
    const float* __restrict__ gkw, const float* __restrict__ gkb,
    u16* __restrict__ kT)
{
  __shared__ u16 L[8][264];
  const int y = blockIdx.x, b = blockIdx.y;   // y = ph*8+py
  const int ph = y >> 3, py = y & 7;
  const int t = threadIdx.x;
  const int px = t >> 5, c8 = (t & 31) * 8;
  const int g = c8 >> 3;
  float mean = statk[b * 32 + g], rstd = statk[256 + b * 32 + g];
  float A[8], Bv[8];
#pragma unroll
  for (int j = 0; j < 8; ++j) {
    A[j] = rstd * gkw[c8 + j];
    Bv[j] = gkb[c8 + j] - mean * A[j];
  }
  const size_t rowbase = (((size_t)b * 128 + y) * 128) * 256;
  const size_t outbase = ((size_t)(b * 16 + ph) * 8 + py) * 32768;
  for (int pw = 0; pw < 16; ++pw) {
    int4 v = *reinterpret_cast<const int4*>(yk + rowbase + (size_t)(pw * 8 + px) * 256 + c8);
    float f[8]; unpack8(v, f);
    u16 o[8];
#pragma unroll
    for (int j = 0; j < 8; ++j) o[j] = f2bf(f[j] * A[j] + Bv[j]);
    *reinterpret_cast<int4*>(&L[px][c8]) = *reinterpret_cast<int4*>(o);
    __syncthreads();
    u16 o2[8];
#pragma unroll
    for (int q = 0; q < 8; ++q) o2[q] = L[q][t];
    *reinterpret_cast<int4*>(kT + outbase + (size_t)(pw * 256 + t) * 8) = *reinterpret_cast<int4*>(o2);
    __syncthreads();
  }
}

// ---------------------------------------------------------------------------
// MFMA attention with fused q-normalization (q~ = (Aq*q+Bq)*Ak on the fly;
// Bk rank-1 term cancels in softmax). One block per patch, 4 waves.
// ---------------------------------------------------------------------------
#define OST 280
__global__ __launch_bounds__(256, 3) void attn_mfma(
    const u16* __restrict__ yq, const u16* __restrict__ yk,
    const u16* __restrict__ kT, const u16* __restrict__ xl,
    const float* __restrict__ statq, const float* __restrict__ statk,
    const float* __restrict__ gqw, const float* __restrict__ gqb,
    const float* __restrict__ gkw,
    u16* __restrict__ resid)
{
  __shared__ __attribute__((aligned(16))) u16 smem[64 * OST + 4 * 16 * 72];
  u16* Ost = smem;                       // [64][OST]
  u16* Pls = smem + 64 * OST;            // 4 x [16][72]

  const int n = blockIdx.x;
  const int b = n >> 8, ph = (n >> 4) & 15, pw = n & 15;
  const int t = threadIdx.x, l = t & 63, w = t >> 6;
  const int lc = l & 15, lg = l >> 4;

  auto tokaddr = [&](int tok) -> size_t {
    return (((size_t)(b * 128 + ph * 8 + (tok >> 3))) * 128 + pw * 8 + (tok & 7)) * 256;
  };

  // ---- QK^T; A-fragments normalized on the fly ----
  const size_t qa = tokaddr(16 * w + lc) + lg * 8;
  bfrag8 aF[8];
#pragma unroll
  for (int ks = 0; ks < 8; ++ks) {
    int c0 = lg * 8 + ks * 32;
    int g = ks * 4 + lg;
    float meanq = statq[b * 32 + g], rstdq = statq[256 + b * 32 + g];
    float rstdk = statk[256 + b * 32 + g];
    int4 v = *reinterpret_cast<const int4*>(yq + qa + ks * 32);
    float f[8]; unpack8(v, f);
    float4 w0 = *reinterpret_cast<const float4*>(gqw + c0);
    float4 w1 = *reinterpret_cast<const float4*>(gqw + c0 + 4);
    float4 b0 = *reinterpret_cast<const float4*>(gqb + c0);
    float4 b1 = *reinterpret_cast<const float4*>(gqb + c0 + 4);
    float4 k0 = *reinterpret_cast<const float4*>(gkw + c0);
    float4 k1 = *reinterpret_cast<const float4*>(gkw + c0 + 4);
    float ww[8] = {w0.x, w0.y, w0.z, w0.w, w1.x, w1.y, w1.z, w1.w};
    float bb[8] = {b0.x, b0.y, b0.z, b0.w, b1.x, b1.y, b1.z, b1.w};
    float kk[8] = {k0.x, k0.y, k0.z, k0.w, k1.x, k1.y, k1.z, k1.w};
    u16 o[8];
#pragma unroll
    for (int j = 0; j < 8; ++j) {
      float Aq = rstdq * ww[j];
      float Bq = bb[j] - meanq * Aq;
      float Ak = rstdk * kk[j];
      o[j] = f2bf((f[j] * Aq + Bq) * Ak);
    }
    aF[ks] = *reinterpret_cast<bfrag8*>(o);
  }

  f32x4 sacc[4];
#pragma unroll
  for (int nt = 0; nt < 4; ++nt) sacc[nt] = (f32x4){0.f, 0.f, 0.f, 0.f};

#pragma unroll
  for (int nt = 0; nt < 4; ++nt) {
    const size_t ka = tokaddr(nt * 16 + lc) + lg * 8;
    bfrag8 bF[8];
#pragma unroll
    for (int ks = 0; ks < 8; ++ks)
      bF[ks] = *reinterpret_cast<const bfrag8*>(yk + ka + ks * 32);
#pragma unroll
    for (int ks = 0; ks < 8; ++ks)
      sacc[nt] = __builtin_amdgcn_mfma_f32_16x16x32_bf16(aF[ks], bF[ks], sacc[nt], 0, 0, 0);
  }

  // ---- softmax over j; scale 1/sqrt(256) = 1/16 ----
  u16* Pw = Pls + w * (16 * 72);
#pragma unroll
  for (int r = 0; r < 4; ++r) {
    float m0 = fmaxf(fmaxf(sacc[0][r], sacc[1][r]), fmaxf(sacc[2][r], sacc[3][r]));
    m0 = fmaxf(m0, __shfl_xor(m0, 1));
    m0 = fmaxf(m0, __shfl_xor(m0, 2));
    m0 = fmaxf(m0, __shfl_xor(m0, 4));
    m0 = fmaxf(m0, __shfl_xor(m0, 8));
    float p0 = __expf((sacc[0][r] - m0) * 0.0625f);
    float p1 = __expf((sacc[1][r] - m0) * 0.0625f);
    float p2 = __expf((sacc[2][r] - m0) * 0.0625f);
    float p3 = __expf((sacc[3][r] - m0) * 0.0625f);
    float s0 = p0 + p1 + p2 + p3;
    s0 += __shfl_xor(s0, 1);
    s0 += __shfl_xor(s0, 2);
    s0 += __shfl_xor(s0, 4);
    s0 += __shfl_xor(s0, 8);
    float inv = 1.f / s0;
    int prow = (lg * 4 + r) * 72;
    Pw[prow + 0 * 16 + lc] = f2bf(p0 * inv);
    Pw[prow + 1 * 16 + lc] = f2bf(p1 * inv);
    Pw[prow + 2 * 16 + lc] = f2bf(p2 * inv);
    Pw[prow + 3 * 16 + lc] = f2bf(p3 * inv);
  }

  // ---- PV: O = P * kN  (B-frags from kT, 16B contiguous) ----
  bfrag8 pA[2];
#pragma unroll
  for (int js = 0; js < 2; ++js)
    pA[js] = *reinterpret_cast<const bfrag8*>(Pw + lc * 72 + js * 32 + lg * 8);

  f32x4 pacc[16];
#pragma unroll
  for (int ct = 0; ct < 16; ++ct) pacc[ct] = (f32x4){0.f, 0.f, 0.f, 0.f};

#pragma unroll
  for (int ct = 0; ct < 16; ++ct) {
    bfrag8 vB[2];
#pragma unroll
    for (int js = 0; js < 2; ++js)
      vB[js] = *reinterpret_cast<const bfrag8*>(
          kT + ((size_t)((b * 16 + ph) * 8 + js * 4 + lg)) * 32768 +
          (size_t)(pw * 256 + ct * 16 + lc) * 8);
#pragma unroll
    for (int js = 0; js < 2; ++js)
      pacc[ct] = __builtin_amdgcn_mfma_f32_16x16x32_bf16(pA[js], vB[js], pacc[ct], 0, 0, 0);
  }

  // ---- epilogue: O -> LDS, then coalesced residual + store ----
#pragma unroll
  for (int ct = 0; ct < 16; ++ct)
#pragma unroll
    for (int r = 0; r < 4; ++r)
      Ost[(16 * w + lg * 4 + r) * OST + ct * 16 + lc] = f2bf(pacc[ct][r]);
  __syncthreads();

#pragma unroll
  for (int s = 0; s < 8; ++s) {
    int px_ = t >> 5;
    int c16 = t & 31;
    size_t g = (((size_t)b * 128 + ph * 8 + s) * 128 + pw * 8 + px_) * 256 + c16 * 8;
    int4 o = *reinterpret_cast<const int4*>(&Ost[(s * 8 + px_) * OST + c16 * 8]);
    int4 r = *reinterpret_cast<const int4*>(xl + g);
    float fo[8], fr[8]; unpack8(o, fo); unpack8(r, fr);
    u16 pk[8];
#pragma unroll
    for (int j = 0; j < 8; ++j) pk[j] = f2bf(fo[j] + fr[j]);
    *reinterpret_cast<int4*>(resid + g) = *reinterpret_cast<int4*>(pk);
  }
}

// ---------------------------------------------------------------------------
// Final GN apply + NHWC bf16 -> NCHW fp32 transpose
// ---------------------------------------------------------------------------
__global__ __launch_bounds__(256) void gnapply_t(
    const u16* __restrict__ Y, const float* __restrict__ stat,
    const float* __restrict__ gw, const float* __restrict__ gb,
    float* __restrict__ out)
{
  const int row = blockIdx.x, b = blockIdx.y;
  const int t = threadIdx.x;
  const int px4 = (t & 31) * 4;
  const int c8 = (t >> 5) * 8;
#pragma unroll
  for (int p = 0; p < 4; ++p) {
    int c0 = p * 64 + c8;
    int g = c0 >> 3;
    float mean = stat[b * 32 + g], rstd = stat[256 + b * 32 + g];
    float A[8], Bv[8];
#pragma unroll
    for (int j = 0; j < 8; ++j) {
      A[j] = rstd * gw[c0 + j];
      Bv[j] = gb[c0 + j] - mean * A[j];
    }
    float vals[4][8];
#pragma unroll
    for (int e = 0; e < 4; ++e) {
      int4 v = *reinterpret_cast<const int4*>(Y + (((size_t)b * 128 + row) * 128 + px4 + e) * 256 + c0);
      float f[8]; unpack8(v, f);
#pragma unroll
      for (int j = 0; j < 8; ++j) vals[e][j] = fmaf(f[j], A[j], Bv[j]);
    }
#pragma unroll
    for (int j = 0; j < 8; ++j) {
      float4 o = {vals[0][j], vals[1][j], vals[2][j], vals[3][j]};
      *reinterpret_cast<float4*>(out + ((size_t)b * 256 + c0 + j) * 16384 + row * 128 + px4) = o;
    }
  }
}

// ---------------------------------------------------------------------------
extern "C" void kernel_launch(void* const* d_in, const int* in_sizes, int n_in,
                              void* d_out, int out_size, void* d_ws, size_t ws_size,
                              hipStream_t stream)
{
  const float* x_low  = (const float*)d_in[0];
  const float* x_high = (const float*)d_in[1];
  const float* w_q    = (const float*)d_in[2];
  const float* gq_w   = (const float*)d_in[3];
  const float* gq_b   = (const float*)d_in[4];
  const float* w_k    = (const float*)d_in[5];
  const float* gk_w   = (const float*)d_in[6];
  const float* gk_b   = (const float*)d_in[7];
  const float* w_o    = (const float*)d_in[8];
  const float* go_w   = (const float*)d_in[9];
  const float* go_b   = (const float*)d_in[10];
  float* out = (float*)d_out;

  char* ws = (char*)d_ws;
  const size_t slot = 67108864;           // 33.55M bf16
  u16* xl  = (u16*)(ws + 0 * slot);       // x_low bf16 NHWC ; later y3
  u16* xh  = (u16*)(ws + 1 * slot);       // x_high bf16 NHWC ; later resid
  u16* yq  = (u16*)(ws + 2 * slot);       // q conv out (raw)
  u16* yk  = (u16*)(ws + 3 * slot);       // k conv out (raw, QK^T B operand)
  u16* kT  = (u16*)(ws + 4 * slot);       // normalized k, patch-transposed
  u16* W2q = (u16*)(ws + 5 * slot);
  u16* W2k = W2q + 589824;
  u16* W2o = W2k + 589824;
  float* partq = (float*)(ws + 5 * slot + 3 * 1179648);
  float* partk = partq + 524288;
  float* parto = partk + 524288;
  float* statq = parto + 524288;
  float* statk = statq + 512;
  float* stato = statk + 512;

  wprep<<<dim3(576, 3), 256, 0, stream>>>(w_q, w_k, w_o, W2q, W2k, W2o);
  xpose<<<dim3(128, 8, 2), 256, 0, stream>>>(x_low, x_high, xl, xh);
  conv_mfma<<<1024, 512, 0, stream>>>(xl, W2q, yq, partq);
  conv_mfma<<<1024, 512, 0, stream>>>(xh, W2k, yk, partk);
  gnstat2b<<<8, 256, 0, stream>>>(partq, statq);
  gnstat2b<<<8, 256, 0, stream>>>(partk, statk);
  normkT<<<dim3(128, 8), 256, 0, stream>>>(yk, statk, gk_w, gk_b, kT);
  attn_mfma<<<2048, 256, 0, stream>>>(yq, yk, kT, xl, statq, statk,
                                      gq_w, gq_b, gk_w, xh);
  conv_mfma<<<1024, 512, 0, stream>>>(xh, W2o, xl, parto);
  gnstat2b<<<8, 256, 0, stream>>>(parto, stato);
  gnapply_t<<<dim3(128, 8), 256, 0, stream>>>(xl, stato, go_w, go_b, out);
}

// Round 6
// 692.266 us; speedup vs baseline: 8.9034x; 1.0021x over previous
//
#include <hip/hip_runtime.h>

using u16 = unsigned short;
using u32 = unsigned int;

typedef short bfrag8 __attribute__((ext_vector_type(8)));   // 8 x bf16
typedef float f32x4  __attribute__((ext_vector_type(4)));

__device__ __forceinline__ void unpack8(const int4 v, float f[8]) {
  u32 a = (u32)v.x, b = (u32)v.y, c = (u32)v.z, d = (u32)v.w;
  f[0] = __uint_as_float(a << 16);
  f[1] = __uint_as_float(a & 0xffff0000u);
  f[2] = __uint_as_float(b << 16);
  f[3] = __uint_as_float(b & 0xffff0000u);
  f[4] = __uint_as_float(c << 16);
  f[5] = __uint_as_float(c & 0xffff0000u);
  f[6] = __uint_as_float(d << 16);
  f[7] = __uint_as_float(d & 0xffff0000u);
}

__device__ __forceinline__ u16 f2bf(float f) {
  u32 u = __float_as_uint(f);
  u32 r = u + 0x7fffu + ((u >> 16) & 1u);
  return (u16)(r >> 16);
}

__device__ __forceinline__ void gload_lds16(const void* g, void* l) {
  __builtin_amdgcn_global_load_lds(
      (const __attribute__((address_space(1))) void*)g,
      (__attribute__((address_space(3))) void*)l, 16, 0, 0);
}

// ---------------------------------------------------------------------------
// Weight prep: fp32 OIHW [256][256][3][3] -> bf16 [9 tap][256 oc][256 ic]
// ---------------------------------------------------------------------------
__global__ __launch_bounds__(256) void wprep(
    const float* __restrict__ wq, const float* __restrict__ wk, const float* __restrict__ wo,
    u16* __restrict__ dq, u16* __restrict__ dk, u16* __restrict__ dwo)
{
  const float* s = (blockIdx.y == 0) ? wq : (blockIdx.y == 1) ? wk : wo;
  u16* d = (blockIdx.y == 0) ? dq : (blockIdx.y == 1) ? dk : dwo;
  int id = blockIdx.x * 256 + threadIdx.x;
  int e = id * 4;                 // output element base: [tap][oc][ic]
  int tap = e >> 16;
  int rem = e & 65535;
  int oc = rem >> 8, ic = rem & 255;
  u16 o[4];
#pragma unroll
  for (int j = 0; j < 4; ++j)
    o[j] = f2bf(s[((size_t)oc * 256 + ic + j) * 9 + tap]);
  *reinterpret_cast<uint2*>(d + e) = *reinterpret_cast<uint2*>(o);
}

// ---------------------------------------------------------------------------
// Transpose-convert: fp32 NCHW -> bf16 NHWC.
// ---------------------------------------------------------------------------
__global__ __launch_bounds__(256) void xpose(
    const float* __restrict__ xa, const float* __restrict__ xb,
    u16* __restrict__ oa, u16* __restrict__ ob)
{
  const int row = blockIdx.x, b = blockIdx.y;
  const float* src = blockIdx.z ? xb : xa;
  u16* dst = blockIdx.z ? ob : oa;
  const int t = threadIdx.x;
  const int px4 = (t >> 3) * 4;     // 0..124
  const int c8 = (t & 7) * 8;       // 0..56
#pragma unroll
  for (int p = 0; p < 4; ++p) {
    int c0 = p * 64 + c8;
    float4 v[8];
#pragma unroll
    for (int j = 0; j < 8; ++j)
      v[j] = *reinterpret_cast<const float4*>(src + ((size_t)b * 256 + c0 + j) * 16384 + row * 128 + px4);
#pragma unroll
    for (int e = 0; e < 4; ++e) {
      u16 o[8];
      o[0] = f2bf(e==0?v[0].x:e==1?v[0].y:e==2?v[0].z:v[0].w);
      o[1] = f2bf(e==0?v[1].x:e==1?v[1].y:e==2?v[1].z:v[1].w);
      o[2] = f2bf(e==0?v[2].x:e==1?v[2].y:e==2?v[2].z:v[2].w);
      o[3] = f2bf(e==0?v[3].x:e==1?v[3].y:e==2?v[3].z:v[3].w);
      o[4] = f2bf(e==0?v[4].x:e==1?v[4].y:e==2?v[4].z:v[4].w);
      o[5] = f2bf(e==0?v[5].x:e==1?v[5].y:e==2?v[5].z:v[5].w);
      o[6] = f2bf(e==0?v[6].x:e==1?v[6].y:e==2?v[6].z:v[6].w);
      o[7] = f2bf(e==0?v[7].x:e==1?v[7].y:e==2?v[7].z:v[7].w);
      *reinterpret_cast<int4*>(dst + (((size_t)b * 128 + row) * 128 + px4 + e) * 256 + c0) =
          *reinterpret_cast<int4*>(o);
    }
  }
}

// ---------------------------------------------------------------------------
// Implicit-GEMM bf16 MFMA conv3x3. 512 thr, 8 waves. Block: 256 oc x 128 px.
// R6: T2 LDS XOR-swizzle (slot(row,q) holds octet q^((row>>1)&3), pre-swizzled
// global source, linear gload_lds dest) + T4 depth-3 A-ring with counted
// vmcnt(2) raw-barrier tap loop (one full drain per chunk) + T5 setprio.
// LDS: Blds [3][132][4][16B] = 25344 | Alds 3 x [256][4][16B] = 49152 -> 74496
// epilogue alias: Ost [128][264]u16 (67584) + sst 4x256 f32 (4096) = 71680
// ---------------------------------------------------------------------------
__global__ __launch_bounds__(512, 4) void conv_mfma(
    const u16* __restrict__ X, const u16* __restrict__ W2, u16* __restrict__ Y,
    float* __restrict__ part)
{
  __shared__ __attribute__((aligned(16))) char csm[74496];

  const int t = threadIdx.x;
  const int l = t & 63;
  const int wv = t >> 6;
  const int id = blockIdx.x;
  const int u = (id & 7) * 128 + (id >> 3);   // XCD-chunk swizzle (bijective)
  const int bb = u >> 7, y0 = u & 127;
  const int och = wv >> 1, pxh = wv & 1;
  const int lc = l & 15, lq = l >> 4;
  const int sa = (lc >> 1) & 3;               // A-read swizzle selector

  f32x4 acc[4][4];
#pragma unroll
  for (int m = 0; m < 4; ++m)
#pragma unroll
    for (int n = 0; n < 4; ++n) acc[m][n] = (f32x4){0.f, 0.f, 0.f, 0.f};

  const size_t xplane = (size_t)bb * (128 * 128 * 256);

  // upfront zeros: halo columns (cidx 0,129) + out-of-range kh planes
  {
    int4 z = {0, 0, 0, 0};
    if (t < 24) {
      int q = t & 3, sel = (t >> 2) & 1, kh = t >> 3;
      int cidx = sel ? 129 : 0;
      *reinterpret_cast<int4*>(csm + ((kh * 132 + cidx) * 4 + q) * 16) = z;
    }
    if (y0 == 0)
      for (int s = t; s < 528; s += 512) *reinterpret_cast<int4*>(csm + s * 16) = z;
    if (y0 == 127)
      for (int s = t; s < 528; s += 512) *reinterpret_cast<int4*>(csm + 16896 + s * 16) = z;
  }

  // A stage: slot idx=(oc,q); source octet q ^ ((oc>>1)&3)  [T2 pre-swizzle]
  auto stageA = [&](int tap, int buf, int ic0) {
#pragma unroll
    for (int i = 0; i < 2; ++i) {
      int idx = t + i * 512;
      int oc = idx >> 2, q = idx & 3;
      int qs = q ^ ((oc >> 1) & 3);
      const u16* src = W2 + (((size_t)(tap * 256 + oc)) << 8) + ic0 + qs * 8;
      gload_lds16(src, csm + 25344 + buf * 16384 + (i * 512 + (t & ~63)) * 16);
    }
  };
  // B stage: slot cidx=px+1; source octet q ^ (((px+1)>>1)&3)
  auto stageB = [&](int ic0) {
#pragma unroll
    for (int i = 0; i < 3; ++i) {
      int idx = t + i * 512;
      int kh = idx >> 9;
      int row = y0 - 1 + kh;
      if (row >= 0 && row < 128) {
        int px = (idx & 511) >> 2, q = idx & 3;
        int qs = q ^ (((px + 1) >> 1) & 3);
        const u16* src = X + xplane + (((size_t)(row * 128 + px)) << 8) + ic0 + qs * 8;
        gload_lds16(src, csm + 64 + kh * 256 + (i * 512 + (t & ~63)) * 16);
      }
    }
  };

  stageB(0);
  stageA(0, 0, 0);
  stageA(1, 1, 0);
  __syncthreads();

  for (int chunk = 0; chunk < 8; ++chunk) {
    const int ic0 = chunk * 32;
#pragma unroll
    for (int tap = 0; tap < 9; ++tap) {
      const int kh = tap / 3, kw = tap % 3, buf = tap % 3;
      if (tap <= 6) stageA(tap + 2, (tap + 2) % 3, ic0);

      bfrag8 af[4], xf[4];
      const int sb = ((lc + kw) >> 1) & 3;
#pragma unroll
      for (int m = 0; m < 4; ++m)
        af[m] = *reinterpret_cast<const bfrag8*>(csm + 25344 + buf * 16384 +
                    (((och * 64 + m * 16 + lc) * 4) + (lq ^ sa)) * 16);
#pragma unroll
      for (int n = 0; n < 4; ++n) {
        int S = pxh * 64 + n * 16 + lc + kw;
        xf[n] = *reinterpret_cast<const bfrag8*>(csm + kh * 8448 + S * 64 + (lq ^ sb) * 16);
      }
      asm volatile("s_waitcnt lgkmcnt(0)" ::: "memory");
      __builtin_amdgcn_sched_barrier(0);
      if (tap <= 6) {
        asm volatile("s_waitcnt vmcnt(2)" ::: "memory");   // tap's A landed; t+2 in flight
      } else if (tap == 7) {
        asm volatile("s_waitcnt vmcnt(0)" ::: "memory");   // A(8) landed
      }
      __builtin_amdgcn_sched_barrier(0);
      __builtin_amdgcn_s_barrier();
      __builtin_amdgcn_sched_barrier(0);

      __builtin_amdgcn_s_setprio(1);
#pragma unroll
      for (int m = 0; m < 4; ++m)
#pragma unroll
        for (int n = 0; n < 4; ++n)
          acc[m][n] = __builtin_amdgcn_mfma_f32_16x16x32_bf16(af[m], xf[n], acc[m][n], 0, 0, 0);
      __builtin_amdgcn_s_setprio(0);
    }
    if (chunk < 7) {
      stageA(0, 0, ic0 + 32);
      stageA(1, 1, ic0 + 32);
      stageB(ic0 + 32);
      __syncthreads();
    }
  }

  // ---- epilogue: acc -> Ost (bf16) + per-channel stat partials ----
  u16* Ost = (u16*)csm;                       // [128 px][264]
  float* sst = (float*)(csm + 67584);         // [2 pxh][2 s/ss][256 c]
  const int chb = och * 64 + lq * 4;
  const int pxb = pxh * 64 + lc;
#pragma unroll
  for (int m = 0; m < 4; ++m)
#pragma unroll
    for (int n = 0; n < 4; ++n) {
      u32 lo = (u32)f2bf(acc[m][n][0]) | ((u32)f2bf(acc[m][n][1]) << 16);
      u32 hi = (u32)f2bf(acc[m][n][2]) | ((u32)f2bf(acc[m][n][3]) << 16);
      uint2 pk = {lo, hi};
      *reinterpret_cast<uint2*>(&Ost[(pxb + n * 16) * 264 + chb + m * 16]) = pk;
    }
#pragma unroll
  for (int m = 0; m < 4; ++m)
#pragma unroll
    for (int r = 0; r < 4; ++r) {
      float s  = acc[m][0][r] + acc[m][1][r] + acc[m][2][r] + acc[m][3][r];
      float ss = acc[m][0][r] * acc[m][0][r] + acc[m][1][r] * acc[m][1][r] +
                 acc[m][2][r] * acc[m][2][r] + acc[m][3][r] * acc[m][3][r];
#pragma unroll
      for (int off = 1; off < 16; off <<= 1) {
        s  += __shfl_xor(s, off);
        ss += __shfl_xor(ss, off);
      }
      if (lc == 0) {
        int c = och * 64 + m * 16 + lq * 4 + r;
        sst[pxh * 512 + c]       = s;
        sst[pxh * 512 + 256 + c] = ss;
      }
    }
  __syncthreads();

  if (t < 256) {
    float s  = sst[t]       + sst[512 + t];
    float ss = sst[256 + t] + sst[768 + t];
    size_t pb = (((size_t)bb * 128 + y0) * 256 + t) * 2;
    part[pb]     = s;
    part[pb + 1] = ss;
  }
#pragma unroll
  for (int s8 = 0; s8 < 8; ++s8) {
    int pix = s8 * 16 + (t >> 5);
    int sub = t & 31;
    int4 v = *reinterpret_cast<const int4*>(&Ost[pix * 264 + sub * 8]);
    *reinterpret_cast<int4*>(Y + xplane + (((size_t)(y0 * 128 + pix)) << 8) + sub * 8) = v;
  }
}

// ---------------------------------------------------------------------------
// Reduce conv's per-row stat partials -> stat[b*32+g] (mean), [256+..] (rstd)
// ---------------------------------------------------------------------------
__global__ __launch_bounds__(256) void gnstat2b(const float* __restrict__ part, float* __restrict__ stat)
{
  const int b = blockIdx.x, t = threadIdx.x;
  float s = 0.f, ss = 0.f;
  for (int row = 0; row < 128; ++row) {
    size_t pb = (((size_t)b * 128 + row) * 256 + t) * 2;
    s  += part[pb];
    ss += part[pb + 1];
  }
  __shared__ float Ls[256], Lss[256];
  Ls[t] = s; Lss[t] = ss;
  __syncthreads();
  if (t < 32) {
    float S = 0.f, SS = 0.f;
#pragma unroll
    for (int j = 0; j < 8; ++j) { S += Ls[t * 8 + j]; SS += Lss[t * 8 + j]; }
    float mean = S * (1.f / 131072.f);
    float var = SS * (1.f / 131072.f) - mean * mean;
    stat[b * 32 + t] = mean;
    stat[256 + b * 32 + t] = rsqrtf(var + 1e-5f);
  }
}

// ---------------------------------------------------------------------------
// normkT: yk (raw NHWC) -> kT = GN(k) in layout [b][ph][py][pw][c][px]
// ---------------------------------------------------------------------------
__global__ __launch_bounds__(256) void normkT(
    const u16* __restrict__ yk, const float* __restrict__ statk,
    const float* __restrict__ gkw, const float* __restrict__ gkb,
    u16* __restrict__ kT)
{
  __shared__ u16 L[8][264];
  const int y = blockIdx.x, b = blockIdx.y;   // y = ph*8+py
  const int ph = y >> 3, py = y & 7;
  const int t = threadIdx.x;
  const int px = t >> 5, c8 = (t & 31) * 8;
  const int g = c8 >> 3;
  float mean = statk[b * 32 + g], rstd = statk[256 + b * 32 + g];
  float A[8], Bv[8];
#pragma unroll
  for (int j = 0; j < 8; ++j) {
    A[j] = rstd * gkw[c8 + j];
    Bv[j] = gkb[c8 + j] - mean * A[j];
  }
  const size_t rowbase = (((size_t)b * 128 + y) * 128) * 256;
  const size_t outbase = ((size_t)(b * 16 + ph) * 8 + py) * 32768;
  for (int pw = 0; pw < 16; ++pw) {
    int4 v = *reinterpret_cast<const int4*>(yk + rowbase + (size_t)(pw * 8 + px) * 256 + c8);
    float f[8]; unpack8(v, f);
    u16 o[8];
#pragma unroll
    for (int j = 0; j < 8; ++j) o[j] = f2bf(f[j] * A[j] + Bv[j]);
    *reinterpret_cast<int4*>(&L[px][c8]) = *reinterpret_cast<int4*>(o);
    __syncthreads();
    u16 o2[8];
#pragma unroll
    for (int q = 0; q < 8; ++q) o2[q] = L[q][t];
    *reinterpret_cast<int4*>(kT + outbase + (size_t)(pw * 256 + t) * 8) = *reinterpret_cast<int4*>(o2);
    __syncthreads();
  }
}

// ---------------------------------------------------------------------------
// MFMA attention with fused q-normalization (q~ = (Aq*q+Bq)*Ak on the fly;
// Bk rank-1 term cancels in softmax). One block per patch, 4 waves.
// ---------------------------------------------------------------------------
#define OST 280
__global__ __launch_bounds__(256, 3) void attn_mfma(
    const u16* __restrict__ yq, const u16* __restrict__ yk,
    const u16* __restrict__ kT, const u16* __restrict__ xl,
    const float* __restrict__ statq, const float* __restrict__ statk,
    const float* __restrict__ gqw, const float* __restrict__ gqb,
    const float* __restrict__ gkw,
    u16* __restrict__ resid)
{
  __shared__ __attribute__((aligned(16))) u16 smem[64 * OST + 4 * 16 * 72];
  u16* Ost = smem;                       // [64][OST]
  u16* Pls = smem + 64 * OST;            // 4 x [16][72]

  const int n = blockIdx.x;
  const int b = n >> 8, ph = (n >> 4) & 15, pw = n & 15;
  const int t = threadIdx.x, l = t & 63, w = t >> 6;
  const int lc = l & 15, lg = l >> 4;

  auto tokaddr = [&](int tok) -> size_t {
    return (((size_t)(b * 128 + ph * 8 + (tok >> 3))) * 128 + pw * 8 + (tok & 7)) * 256;
  };

  // ---- QK^T; A-fragments normalized on the fly ----
  const size_t qa = tokaddr(16 * w + lc) + lg * 8;
  bfrag8 aF[8];
#pragma unroll
  for (int ks = 0; ks < 8; ++ks) {
    int c0 = lg * 8 + ks * 32;
    int g = ks * 4 + lg;
    float meanq = statq[b * 32 + g], rstdq = statq[256 + b * 32 + g];
    float rstdk = statk[256 + b * 32 + g];
    int4 v = *reinterpret_cast<const int4*>(yq + qa + ks * 32);
    float f[8]; unpack8(v, f);
    float4 w0 = *reinterpret_cast<const float4*>(gqw + c0);
    float4 w1 = *reinterpret_cast<const float4*>(gqw + c0 + 4);
    float4 b0 = *reinterpret_cast<const float4*>(gqb + c0);
    float4 b1 = *reinterpret_cast<const float4*>(gqb + c0 + 4);
    float4 k0 = *reinterpret_cast<const float4*>(gkw + c0);
    float4 k1 = *reinterpret_cast<const float4*>(gkw + c0 + 4);
    float ww[8] = {w0.x, w0.y, w0.z, w0.w, w1.x, w1.y, w1.z, w1.w};
    float bb[8] = {b0.x, b0.y, b0.z, b0.w, b1.x, b1.y, b1.z, b1.w};
    float kk[8] = {k0.x, k0.y, k0.z, k0.w, k1.x, k1.y, k1.z, k1.w};
    u16 o[8];
#pragma unroll
    for (int j = 0; j < 8; ++j) {
      float Aq = rstdq * ww[j];
      float Bq = bb[j] - meanq * Aq;
      float Ak = rstdk * kk[j];
      o[j] = f2bf((f[j] * Aq + Bq) * Ak);
    }
    aF[ks] = *reinterpret_cast<bfrag8*>(o);
  }

  f32x4 sacc[4];
#pragma unroll
  for (int nt = 0; nt < 4; ++nt) sacc[nt] = (f32x4){0.f, 0.f, 0.f, 0.f};

#pragma unroll
  for (int nt = 0; nt < 4; ++nt) {
    const size_t ka = tokaddr(nt * 16 + lc) + lg * 8;
    bfrag8 bF[8];
#pragma unroll
    for (int ks = 0; ks < 8; ++ks)
      bF[ks] = *reinterpret_cast<const bfrag8*>(yk + ka + ks * 32);
#pragma unroll
    for (int ks = 0; ks < 8; ++ks)
      sacc[nt] = __builtin_amdgcn_mfma_f32_16x16x32_bf16(aF[ks], bF[ks], sacc[nt], 0, 0, 0);
  }

  // ---- softmax over j; scale 1/sqrt(256) = 1/16 ----
  u16* Pw = Pls + w * (16 * 72);
#pragma unroll
  for (int r = 0; r < 4; ++r) {
    float m0 = fmaxf(fmaxf(sacc[0][r], sacc[1][r]), fmaxf(sacc[2][r], sacc[3][r]));
    m0 = fmaxf(m0, __shfl_xor(m0, 1));
    m0 = fmaxf(m0, __shfl_xor(m0, 2));
    m0 = fmaxf(m0, __shfl_xor(m0, 4));
    m0 = fmaxf(m0, __shfl_xor(m0, 8));
    float p0 = __expf((sacc[0][r] - m0) * 0.0625f);
    float p1 = __expf((sacc[1][r] - m0) * 0.0625f);
    float p2 = __expf((sacc[2][r] - m0) * 0.0625f);
    float p3 = __expf((sacc[3][r] - m0) * 0.0625f);
    float s0 = p0 + p1 + p2 + p3;
    s0 += __shfl_xor(s0, 1);
    s0 += __shfl_xor(s0, 2);
    s0 += __shfl_xor(s0, 4);
    s0 += __shfl_xor(s0, 8);
    float inv = 1.f / s0;
    int prow = (lg * 4 + r) * 72;
    Pw[prow + 0 * 16 + lc] = f2bf(p0 * inv);
    Pw[prow + 1 * 16 + lc] = f2bf(p1 * inv);
    Pw[prow + 2 * 16 + lc] = f2bf(p2 * inv);
    Pw[prow + 3 * 16 + lc] = f2bf(p3 * inv);
  }

  // ---- PV: O = P * kN  (B-frags from kT, 16B contiguous) ----
  bfrag8 pA[2];
#pragma unroll
  for (int js = 0; js < 2; ++js)
    pA[js] = *reinterpret_cast<const bfrag8*>(Pw + lc * 72 + js * 32 + lg * 8);

  f32x4 pacc[16];
#pragma unroll
  for (int ct = 0; ct < 16; ++ct) pacc[ct] = (f32x4){0.f, 0.f, 0.f, 0.f};

#pragma unroll
  for (int ct = 0; ct < 16; ++ct) {
    bfrag8 vB[2];
#pragma unroll
    for (int js = 0; js < 2; ++js)
      vB[js] = *reinterpret_cast<const bfrag8*>(
          kT + ((size_t)((b * 16 + ph) * 8 + js * 4 + lg)) * 32768 +
          (size_t)(pw * 256 + ct * 16 + lc) * 8);
#pragma unroll
    for (int js = 0; js < 2; ++js)
      pacc[ct] = __builtin_amdgcn_mfma_f32_16x16x32_bf16(pA[js], vB[js], pacc[ct], 0, 0, 0);
  }

  // ---- epilogue: O -> LDS, then coalesced residual + store ----
#pragma unroll
  for (int ct = 0; ct < 16; ++ct)
#pragma unroll
    for (int r = 0; r < 4; ++r)
      Ost[(16 * w + lg * 4 + r) * OST + ct * 16 + lc] = f2bf(pacc[ct][r]);
  __syncthreads();

#pragma unroll
  for (int s = 0; s < 8; ++s) {
    int px_ = t >> 5;
    int c16 = t & 31;
    size_t g = (((size_t)b * 128 + ph * 8 + s) * 128 + pw * 8 + px_) * 256 + c16 * 8;
    int4 o = *reinterpret_cast<const int4*>(&Ost[(s * 8 + px_) * OST + c16 * 8]);
    int4 r = *reinterpret_cast<const int4*>(xl + g);
    float fo[8], fr[8]; unpack8(o, fo); unpack8(r, fr);
    u16 pk[8];
#pragma unroll
    for (int j = 0; j < 8; ++j) pk[j] = f2bf(fo[j] + fr[j]);
    *reinterpret_cast<int4*>(resid + g) = *reinterpret_cast<int4*>(pk);
  }
}

// ---------------------------------------------------------------------------
// Final GN apply + NHWC bf16 -> NCHW fp32 transpose
// ---------------------------------------------------------------------------
__global__ __launch_bounds__(256) void gnapply_t(
    const u16* __restrict__ Y, const float* __restrict__ stat,
    const float* __restrict__ gw, const float* __restrict__ gb,
    float* __restrict__ out)
{
  const int row = blockIdx.x, b = blockIdx.y;
  const int t = threadIdx.x;
  const int px4 = (t & 31) * 4;
  const int c8 = (t >> 5) * 8;
#pragma unroll
  for (int p = 0; p < 4; ++p) {
    int c0 = p * 64 + c8;
    int g = c0 >> 3;
    float mean = stat[b * 32 + g], rstd = stat[256 + b * 32 + g];
    float A[8], Bv[8];
#pragma unroll
    for (int j = 0; j < 8; ++j) {
      A[j] = rstd * gw[c0 + j];
      Bv[j] = gb[c0 + j] - mean * A[j];
    }
    float vals[4][8];
#pragma unroll
    for (int e = 0; e < 4; ++e) {
      int4 v = *reinterpret_cast<const int4*>(Y + (((size_t)b * 128 + row) * 128 + px4 + e) * 256 + c0);
      float f[8]; unpack8(v, f);
#pragma unroll
      for (int j = 0; j < 8; ++j) vals[e][j] = fmaf(f[j], A[j], Bv[j]);
    }
#pragma unroll
    for (int j = 0; j < 8; ++j) {
      float4 o = {vals[0][j], vals[1][j], vals[2][j], vals[3][j]};
      *reinterpret_cast<float4*>(out + ((size_t)b * 256 + c0 + j) * 16384 + row * 128 + px4) = o;
    }
  }
}

// ---------------------------------------------------------------------------
extern "C" void kernel_launch(void* const* d_in, const int* in_sizes, int n_in,
                              void* d_out, int out_size, void* d_ws, size_t ws_size,
                              hipStream_t stream)
{
  const float* x_low  = (const float*)d_in[0];
  const float* x_high = (const float*)d_in[1];
  const float* w_q    = (const float*)d_in[2];
  const float* gq_w   = (const float*)d_in[3];
  const float* gq_b   = (const float*)d_in[4];
  const float* w_k    = (const float*)d_in[5];
  const float* gk_w   = (const float*)d_in[6];
  const float* gk_b   = (const float*)d_in[7];
  const float* w_o    = (const float*)d_in[8];
  const float* go_w   = (const float*)d_in[9];
  const float* go_b   = (const float*)d_in[10];
  float* out = (float*)d_out;

  char* ws = (char*)d_ws;
  const size_t slot = 67108864;           // 33.55M bf16
  u16* xl  = (u16*)(ws + 0 * slot);       // x_low bf16 NHWC ; later y3
  u16* xh  = (u16*)(ws + 1 * slot);       // x_high bf16 NHWC ; later resid
  u16* yq  = (u16*)(ws + 2 * slot);       // q conv out (raw)
  u16* yk  = (u16*)(ws + 3 * slot);       // k conv out (raw, QK^T B operand)
  u16* kT  = (u16*)(ws + 4 * slot);       // normalized k, patch-transposed
  u16* W2q = (u16*)(ws + 5 * slot);
  u16* W2k = W2q + 589824;
  u16* W2o = W2k + 589824;
  float* partq = (float*)(ws + 5 * slot + 3 * 1179648);
  float* partk = partq + 524288;
  float* parto = partk + 524288;
  float* statq = parto + 524288;
  float* statk = statq + 512;
  float* stato = statk + 512;

  wprep<<<dim3(576, 3), 256, 0, stream>>>(w_q, w_k, w_o, W2q, W2k, W2o);
  xpose<<<dim3(128, 8, 2), 256, 0, stream>>>(x_low, x_high, xl, xh);
  conv_mfma<<<1024, 512, 0, stream>>>(xl, W2q, yq, partq);
  conv_mfma<<<1024, 512, 0, stream>>>(xh, W2k, yk, partk);
  gnstat2b<<<8, 256, 0, stream>>>(partq, statq);
  gnstat2b<<<8, 256, 0, stream>>>(partk, statk);
  normkT<<<dim3(128, 8), 256, 0, stream>>>(yk, statk, gk_w, gk_b, kT);
  attn_mfma<<<2048, 256, 0, stream>>>(yq, yk, kT, xl, statq, statk,
                                      gq_w, gq_b, gk_w, xh);
  conv_mfma<<<1024, 512, 0, stream>>>(xh, W2o, xl, parto);
  gnstat2b<<<8, 256, 0, stream>>>(parto, stato);
  gnapply_t<<<dim3(128, 8), 256, 0, stream>>>(xl, stato, go_w, go_b, out);
}